// Round 6
// baseline (1271.746 us; speedup 1.0000x reference)
//
#include <hip/hip_runtime.h>
#include <hip/hip_fp16.h>

#define NN 50000
#define NP 400000
#define NEDGE 800000
#define IND 256
#define HD 128
#define NC 10
#define TBP 10
#define SCAN_NB 196  // ceil(NN/256)

typedef _Float16 f16;
typedef _Float16 f16x4 __attribute__((ext_vector_type(4)));
typedef _Float16 f16x8 __attribute__((ext_vector_type(8)));
typedef unsigned short u16x8 __attribute__((ext_vector_type(8)));
typedef float f32x4 __attribute__((ext_vector_type(4)));

// ---- workspace offsets (bytes) ----
static constexpr size_t OFF_R      = 0;          // 128 f32: R[100], [100]=alpha
static constexpr size_t OFF_H      = 512;        // h fp16 [NN][128] (dead after edge_mlp)
static constexpr size_t OFF_OFFS   = 512;            // CSR off int[NN+1]   (aliases h)
static constexpr size_t OFF_CUR    = 512 + 200016;   // CSR cursor int[NN]  (aliases h)
static constexpr size_t OFF_CSR    = 512 + 400032;   // CSR edge ids int[NEDGE] (aliases h)
static constexpr size_t OFF_BSUM   = 512 + 3600032;  // int[256] block sums (aliases h)
static constexpr size_t OFF_BBASE  = 512 + 3601056;  // int[256] block bases (aliases h)
static constexpr size_t OFF_LOGPHI = 12800512;   // [NN][10] f32
static constexpr size_t OFF_DEG    = 14800512;   // [NN] f32
static constexpr size_t OFF_LOGDEG = 15000512;   // [NN] f32
static constexpr size_t OFF_RSQ    = 15200512;   // [NN] f32
static constexpr size_t OFF_WPAIR  = 15400512;   // [NP] f32
static constexpr size_t OFF_EN     = 17000512;   // [NP] f32
static constexpr size_t OFF_M      = 18600512;   // m edge-major [NEDGE][10] f32 (32MB)
static constexpr size_t OFF_L      = 50600512;   // log_f edge-major [NEDGE][10] f32 (32MB)
static constexpr size_t OFF_SUMIN  = 82600512;   // [NN][10] f32
static constexpr size_t OFF_W1T    = 84600512;   // W1 transposed fp16 [64][256]

// ---------------- setup: R matrix, alpha, W1 transpose ----------------
__global__ __launch_bounds__(256) void k_setup(const float* __restrict__ Rraw,
    const float* __restrict__ rsl, const float* __restrict__ ml,
    const float* __restrict__ mw1, float* __restrict__ Rbuf, f16* __restrict__ w1t) {
  int tid = threadIdx.x;
  if (tid < 100) {
    int c = tid / 10, d = tid % 10;
    float scale = log1pf(expf(rsl[0])) + 1e-6f;
    Rbuf[tid] = scale * tanhf(0.5f * (Rraw[c * 10 + d] + Rraw[d * 10 + c]));
  } else if (tid == 100) {
    Rbuf[100] = 1.5f * (1.f / (1.f + expf(-ml[0])));  // ALPHA_MAX*sigmoid*ALPHA_SCALE
  }
  for (int idx = tid; idx < 64 * 256; idx += 256) {
    int j = idx >> 8, k = idx & 255;
    w1t[idx] = (f16)mw1[k * 64 + j];
  }
}

// ---------------- degree / node post ----------------
__global__ __launch_bounds__(256) void k_deg(const int* __restrict__ ei, float* __restrict__ deg) {
  int e = blockIdx.x * 256 + threadIdx.x;
  if (e < NEDGE) atomicAdd(&deg[ei[e]], 1.f);
}

__global__ __launch_bounds__(256) void k_nodepost(const float* __restrict__ deg,
    float* __restrict__ logdeg, float* __restrict__ rsq) {
  int i = blockIdx.x * 256 + threadIdx.x;
  if (i >= NN) return;
  float d = deg[i];
  logdeg[i] = __logf(d + 1.f);
  rsq[i] = rsqrtf(fmaxf(d, 1.f));
}

// ---------------- CSR build: 3-phase hierarchical scan ----------------
__global__ __launch_bounds__(256) void k_scan1(const float* __restrict__ deg,
    int* __restrict__ bsum) {
  int idx = blockIdx.x * 256 + threadIdx.x;
  int v = (idx < NN) ? (int)deg[idx] : 0;
#pragma unroll
  for (int o = 32; o; o >>= 1) v += __shfl_down(v, o);
  __shared__ int wsum[4];
  if ((threadIdx.x & 63) == 0) wsum[threadIdx.x >> 6] = v;
  __syncthreads();
  if (threadIdx.x == 0) bsum[blockIdx.x] = wsum[0] + wsum[1] + wsum[2] + wsum[3];
}

__global__ __launch_bounds__(256) void k_scan2(const int* __restrict__ bsum,
    int* __restrict__ bbase) {
  __shared__ int s[256];
  int t = threadIdx.x;
  int orig = (t < SCAN_NB) ? bsum[t] : 0;
  s[t] = orig;
  __syncthreads();
  for (int d = 1; d < 256; d <<= 1) {
    int v = (t >= d) ? s[t - d] : 0;
    __syncthreads();
    s[t] += v;
    __syncthreads();
  }
  bbase[t] = s[t] - orig;  // exclusive
}

__global__ __launch_bounds__(256) void k_scan3(const float* __restrict__ deg,
    const int* __restrict__ bbase, int* __restrict__ off, int* __restrict__ cursor) {
  __shared__ int s[256];
  int t = threadIdx.x;
  int idx = blockIdx.x * 256 + t;
  int d = (idx < NN) ? (int)deg[idx] : 0;
  s[t] = d;
  __syncthreads();
  for (int k = 1; k < 256; k <<= 1) {
    int v = (t >= k) ? s[t - k] : 0;
    __syncthreads();
    s[t] += v;
    __syncthreads();
  }
  int base = bbase[blockIdx.x];
  int excl = base + s[t] - d;
  if (idx < NN) {
    off[idx] = excl;
    cursor[idx] = excl;
  }
  if (idx == NN - 1) off[NN] = excl + d;
}

__global__ __launch_bounds__(256) void k_fill(const int* __restrict__ ei,
    int* __restrict__ cursor, int* __restrict__ csr) {
  int e = blockIdx.x * 256 + threadIdx.x;
  if (e >= NEDGE) return;
  int d = ei[NEDGE + e];
  int pos = atomicAdd(&cursor[d], 1);
  csr[pos] = e;
}

// ---------------- encoder: h = relu(x @ W1 + b1), 4x4 register tile ----------------
__global__ __launch_bounds__(256) void k_encoder(const float* __restrict__ x,
    const float* __restrict__ w1, const float* __restrict__ b1, f16* __restrict__ h) {
  __shared__ float xs[32 * IND];  // 32 KB
  const int tid = threadIdx.x;
  const int nb = blockIdx.x * 32;
  {
    const f32x4* src = (const f32x4*)(x + (size_t)nb * IND);
    f32x4* dst4 = (f32x4*)xs;
#pragma unroll
    for (int i = 0; i < 8; i++) {
      int fidx = tid + 256 * i;
      int row = fidx >> 6;
      f32x4 v = {0.f, 0.f, 0.f, 0.f};
      if (nb + row < NN) v = src[fidx];
      dst4[fidx] = v;
    }
  }
  __syncthreads();
  const int j0 = (tid & 31) * 4;   // 4 output cols
  const int r0 = (tid >> 5) * 4;   // 4 rows (within block)
  float acc[4][4] = {};
  const f32x4* xs4 = (const f32x4*)xs;
  for (int k0 = 0; k0 < IND; k0 += 4) {
    f32x4 xv[4], wv[4];
#pragma unroll
    for (int rr = 0; rr < 4; rr++) xv[rr] = xs4[(r0 + rr) * (IND / 4) + (k0 >> 2)];
#pragma unroll
    for (int kk = 0; kk < 4; kk++) wv[kk] = *(const f32x4*)(w1 + (size_t)(k0 + kk) * HD + j0);
#pragma unroll
    for (int kk = 0; kk < 4; kk++)
#pragma unroll
      for (int rr = 0; rr < 4; rr++)
#pragma unroll
        for (int jj = 0; jj < 4; jj++)
          acc[rr][jj] += xv[rr][kk] * wv[kk][jj];
  }
  float bj[4] = {b1[j0], b1[j0 + 1], b1[j0 + 2], b1[j0 + 3]};
#pragma unroll
  for (int rr = 0; rr < 4; rr++) {
    int row = nb + r0 + rr;
    if (row < NN) {
      f16x4 o;
#pragma unroll
      for (int jj = 0; jj < 4; jj++) o[jj] = (f16)fmaxf(acc[rr][jj] + bj[jj], 0.f);
      *(f16x4*)(h + (size_t)row * HD + j0) = o;
    }
  }
}

// ---------------- logits + log_softmax(logits/1.5) ----------------
__global__ __launch_bounds__(256) void k_logits(const f16* __restrict__ h,
    const float* __restrict__ w2, const float* __restrict__ b2, float* __restrict__ logphi) {
  __shared__ float hs[16 * HD];
  __shared__ float lg[16 * NC];
  const int tid = threadIdx.x;
  const int nb = blockIdx.x * 16;
  for (int i = tid; i < 16 * HD / 8; i += 256) {
    f16x8 v = *(const f16x8*)(h + (size_t)nb * HD + i * 8);
#pragma unroll
    for (int u = 0; u < 8; u++) hs[i * 8 + u] = (float)v[u];
  }
  __syncthreads();
  if (tid < 160) {
    int n = tid / 10, c = tid % 10;
    float a = b2[c];
    for (int k = 0; k < HD; k++) a += hs[n * HD + k] * w2[k * NC + c];
    lg[n * NC + c] = a * (1.f / 1.5f);
  }
  __syncthreads();
  if (tid < 16) {
    float mx = -1e30f;
#pragma unroll
    for (int c = 0; c < NC; c++) mx = fmaxf(mx, lg[tid * NC + c]);
    float s = 0.f;
#pragma unroll
    for (int c = 0; c < NC; c++) s += __expf(lg[tid * NC + c] - mx);
    float lse = __logf(s) + mx;
#pragma unroll
    for (int c = 0; c < NC; c++)
      logphi[(size_t)(nb + tid) * NC + c] = lg[tid * NC + c] - lse;
  }
}

// ---------------- edge MLP (per undirected pair), MFMA f16 ----------------
__global__ __launch_bounds__(256) void k_edge_mlp(const f16* __restrict__ h,
    const int* __restrict__ ei, const float* __restrict__ logdeg, const float* __restrict__ rsq,
    const f16* __restrict__ w1t, const float* __restrict__ mw1, const float* __restrict__ mb1,
    const float* __restrict__ mw2, const float* __restrict__ mb2,
    float* __restrict__ w_pair, float* __restrict__ en_pair) {
  __shared__ f16 At[4][16 * 264];
  __shared__ float hidl[4][16 * 64];
  __shared__ float sfeat[4][2][16];
  const int tid = threadIdx.x;
  const int wid = tid >> 6;
  const int lane = tid & 63;
  const int l15 = lane & 15;
  const int lhi = lane >> 4;

  f16x8 bfr[8][4];
#pragma unroll
  for (int ks = 0; ks < 8; ks++)
#pragma unroll
    for (int t = 0; t < 4; t++)
      bfr[ks][t] = *(const f16x8*)(w1t + (size_t)(l15 + 16 * t) * 256 + ks * 32 + lhi * 8);

  float b1v[4], w256v[4], w257v[4];
#pragma unroll
  for (int t = 0; t < 4; t++) {
    b1v[t] = mb1[l15 + 16 * t];
    w256v[t] = mw1[256 * 64 + l15 + 16 * t];
    w257v[t] = mw1[257 * 64 + l15 + 16 * t];
  }
  float w2r[16];
#pragma unroll
  for (int jj = 0; jj < 16; jj++) w2r[jj] = mw2[lhi * 16 + jj];
  const float b2s = mb2[0];

  const int ntiles = NP / 64;  // 6250
  for (int tile = blockIdx.x; tile < ntiles; tile += gridDim.x) {
    const int pbase = tile * 64 + wid * 16;
#pragma unroll
    for (int rr = 0; rr < 4; rr++) {
      int r = rr * 4 + lhi;
      int p = pbase + r;
      int s = ei[p], d = ei[NEDGE + p];
      f16x8 hv = *(const f16x8*)(h + (size_t)s * HD + l15 * 8);
      f16x8 gv = *(const f16x8*)(h + (size_t)d * HD + l15 * 8);
      f16x8 pv = hv * gv;
      f16x8 qv = hv - gv;
      u16x8 qb = *(u16x8*)&qv;
#pragma unroll
      for (int u = 0; u < 8; u++) qb[u] &= 0x7FFF;
      qv = *(f16x8*)&qb;
      *(f16x8*)(&At[wid][r * 264 + l15 * 8]) = pv;
      *(f16x8*)(&At[wid][r * 264 + 128 + l15 * 8]) = qv;
    }
    if (lane < 16) {
      int p = pbase + lane;
      int s = ei[p], d = ei[NEDGE + p];
      float a = logdeg[s], b = logdeg[d];
      sfeat[wid][0][lane] = a + b;
      sfeat[wid][1][lane] = fabsf(a - b);
      en_pair[p] = rsq[s] * rsq[d];
    }
    __syncthreads();
    f32x4 acc[4] = {{0.f, 0.f, 0.f, 0.f}, {0.f, 0.f, 0.f, 0.f},
                    {0.f, 0.f, 0.f, 0.f}, {0.f, 0.f, 0.f, 0.f}};
#pragma unroll
    for (int ks = 0; ks < 8; ks++) {
      f16x8 af = *(const f16x8*)(&At[wid][l15 * 264 + ks * 32 + lhi * 8]);
#pragma unroll
      for (int t = 0; t < 4; t++)
        acc[t] = __builtin_amdgcn_mfma_f32_16x16x32_f16(af, bfr[ks][t], acc[t], 0, 0, 0);
    }
#pragma unroll
    for (int t = 0; t < 4; t++) {
#pragma unroll
      for (int i = 0; i < 4; i++) {
        int r = lhi * 4 + i;
        float v = acc[t][i] + sfeat[wid][0][r] * w256v[t] + sfeat[wid][1][r] * w257v[t] + b1v[t];
        hidl[wid][r * 64 + l15 + 16 * t] = fmaxf(v, 0.f);
      }
    }
    __syncthreads();
    {
      float sacc = 0.f;
#pragma unroll
      for (int jj = 0; jj < 16; jj++) sacc += hidl[wid][l15 * 64 + lhi * 16 + jj] * w2r[jj];
      sacc += __shfl_xor(sacc, 16);
      sacc += __shfl_xor(sacc, 32);
      if (lane < 16) {
        float wr = sacc + b2s;
        w_pair[pbase + lane] = 0.8f / (1.f + __expf(-wr));
      }
    }
    __syncthreads();
  }
}

// ---------------- m0 = exp(log_phi[src]) (edge-major) ----------------
__global__ __launch_bounds__(256) void k_m0(const int* __restrict__ ei,
    const float* __restrict__ logphi, float* __restrict__ m) {
  int e = blockIdx.x * 256 + threadIdx.x;
  if (e >= NEDGE) return;
  int s = ei[e];
  float2* mp = (float2*)(m + (size_t)e * 10);
  const float2* lp = (const float2*)(logphi + (size_t)s * 10);
#pragma unroll
  for (int i = 0; i < 5; i++) {
    float2 v = lp[i];
    float2 o;
    o.x = __expf(v.x);
    o.y = __expf(v.y);
    mp[i] = o;
  }
}

// ---------------- initial L: f from m0 (per directed edge, no atomics) ----------------
__global__ __launch_bounds__(256) void k_bp_f(const float* __restrict__ m,
    const float* __restrict__ wp, const float* __restrict__ enp,
    const float* __restrict__ Rbuf, float* __restrict__ L) {
  __shared__ float Rs[100];
  if (threadIdx.x < 100) Rs[threadIdx.x] = Rbuf[threadIdx.x];
  __syncthreads();
  int e = blockIdx.x * 256 + threadIdx.x;
  if (e >= NEDGE) return;
  int p = (e < NP) ? e : e - NP;
  float w = wp[p], en = enp[p];
  float mr[10];
  {
    const float2* mp = (const float2*)(m + (size_t)e * 10);
#pragma unroll
    for (int i = 0; i < 5; i++) { float2 v = mp[i]; mr[2 * i] = v.x; mr[2 * i + 1] = v.y; }
  }
  float f[10] = {0, 0, 0, 0, 0, 0, 0, 0, 0, 0};
#pragma unroll
  for (int c = 0; c < NC; c++) {
    float Ecc = __expf(w * Rs[c * NC + c]);
    f[c] += mr[c] * Ecc;
#pragma unroll
    for (int d = c + 1; d < NC; d++) {
      float Ecd = __expf(w * Rs[c * NC + d]);
      f[d] += mr[c] * Ecd;
      f[c] += mr[d] * Ecd;
    }
  }
  float2* Lp = (float2*)(L + (size_t)e * 10);
#pragma unroll
  for (int i = 0; i < 5; i++) {
    float2 o;
    o.x = __logf(fmaxf(f[2 * i], 1e-12f)) * en;
    o.y = __logf(fmaxf(f[2 * i + 1], 1e-12f)) * en;
    Lp[i] = o;
  }
}

// ---------------- gather segment-reduce: sum_in[n][c] = sum L[incoming][c] ----------------
__global__ __launch_bounds__(256) void k_gather(const float* __restrict__ L,
    const int* __restrict__ csr, const int* __restrict__ off, float* __restrict__ sumin) {
  int wave = (blockIdx.x * 256 + threadIdx.x) >> 6;
  int lane = threadIdx.x & 63;
  int nl = lane / 10;   // 0..5 (6 nodes per wave), lanes 60..63 idle
  int c = lane % 10;
  int n = wave * 6 + nl;
  if (nl >= 6 || n >= NN) return;
  int o0 = off[n], o1 = off[n + 1];
  float acc = 0.f;
  for (int k = o0; k < o1; k++) {
    int e = csr[k];
    acc += L[(size_t)e * 10 + c];
  }
  sumin[(size_t)n * 10 + c] = acc;
}

// ---------------- fused BP step (per undirected pair): upd both dirs + new L ----------------
__global__ __launch_bounds__(256) void k_bp_fused(float* __restrict__ m,
    float* __restrict__ L, const float* __restrict__ sumin,
    const float* __restrict__ logphi, const int* __restrict__ ei,
    const float* __restrict__ wp, const float* __restrict__ enp,
    const float* __restrict__ Rbuf) {
  __shared__ float Rs[104];
  if (threadIdx.x < 101) Rs[threadIdx.x] = Rbuf[threadIdx.x];
  __syncthreads();
  int p = blockIdx.x * 256 + threadIdx.x;
  if (p >= NP) return;
  const float alpha = Rs[100];
  const int s = ei[p], d = ei[NEDGE + p];
  const float w = wp[p], en = enp[p];

  float Le[10], Lr[10];
  {
    const float2* a = (const float2*)(L + (size_t)p * 10);
    const float2* b = (const float2*)(L + (size_t)(p + NP) * 10);
#pragma unroll
    for (int i = 0; i < 5; i++) {
      float2 u = a[i], v = b[i];
      Le[2 * i] = u.x; Le[2 * i + 1] = u.y;
      Lr[2 * i] = v.x; Lr[2 * i + 1] = v.y;
    }
  }
  // t_e: edge p (src=s): logphi[s] + alpha*(sumin[s] - L[re]); t_r: edge p+NP (src=d)
  float te[10], tr[10];
  float mxe = -1e30f, mxr = -1e30f;
  {
    const float2* sis = (const float2*)(sumin + (size_t)s * 10);
    const float2* sid = (const float2*)(sumin + (size_t)d * 10);
    const float2* lps = (const float2*)(logphi + (size_t)s * 10);
    const float2* lpd = (const float2*)(logphi + (size_t)d * 10);
#pragma unroll
    for (int i = 0; i < 5; i++) {
      float2 ss = sis[i], sd = sid[i], ps = lps[i], pd = lpd[i];
      float e0 = ps.x + alpha * (ss.x - Lr[2 * i]);
      float e1 = ps.y + alpha * (ss.y - Lr[2 * i + 1]);
      float r0 = pd.x + alpha * (sd.x - Le[2 * i]);
      float r1 = pd.y + alpha * (sd.y - Le[2 * i + 1]);
      te[2 * i] = e0; te[2 * i + 1] = e1;
      tr[2 * i] = r0; tr[2 * i + 1] = r1;
      mxe = fmaxf(mxe, fmaxf(e0, e1));
      mxr = fmaxf(mxr, fmaxf(r0, r1));
    }
  }
  float se = 0.f, sr = 0.f;
#pragma unroll
  for (int c = 0; c < NC; c++) {
    float ve = __expf(te[c] - mxe);
    float vr = __expf(tr[c] - mxr);
    te[c] = ve; tr[c] = vr;
    se += ve; sr += vr;
  }
  const float ie = 0.2f / se, ir = 0.2f / sr;
  // mix with old m, renorm, write
  float me[10], mr[10];
  float nse = 0.f, nsr = 0.f;
  {
    float2* mpe = (float2*)(m + (size_t)p * 10);
    float2* mpr = (float2*)(m + (size_t)(p + NP) * 10);
#pragma unroll
    for (int i = 0; i < 5; i++) {
      float2 u = mpe[i], v = mpr[i];
      float a0 = fmaxf(0.8f * u.x + te[2 * i] * ie, 1e-12f);
      float a1 = fmaxf(0.8f * u.y + te[2 * i + 1] * ie, 1e-12f);
      float b0 = fmaxf(0.8f * v.x + tr[2 * i] * ir, 1e-12f);
      float b1 = fmaxf(0.8f * v.y + tr[2 * i + 1] * ir, 1e-12f);
      me[2 * i] = a0; me[2 * i + 1] = a1;
      mr[2 * i] = b0; mr[2 * i + 1] = b1;
      nse += a0 + a1; nsr += b0 + b1;
    }
    const float qe = 1.f / nse, qr = 1.f / nsr;
#pragma unroll
    for (int i = 0; i < 5; i++) {
      float2 u, v;
      u.x = me[2 * i] * qe; u.y = me[2 * i + 1] * qe;
      v.x = mr[2 * i] * qr; v.y = mr[2 * i + 1] * qr;
      me[2 * i] = u.x; me[2 * i + 1] = u.y;
      mr[2 * i] = v.x; mr[2 * i + 1] = v.y;
      mpe[i] = u; mpr[i] = v;
    }
  }
  // new L for both directions: K symmetric -> same E serves both
  float fe[10] = {0, 0, 0, 0, 0, 0, 0, 0, 0, 0};
  float fr[10] = {0, 0, 0, 0, 0, 0, 0, 0, 0, 0};
#pragma unroll
  for (int c = 0; c < NC; c++) {
    float Ecc = __expf(w * Rs[c * NC + c]);
    fe[c] += me[c] * Ecc;
    fr[c] += mr[c] * Ecc;
#pragma unroll
    for (int dd = c + 1; dd < NC; dd++) {
      float E = __expf(w * Rs[c * NC + dd]);
      fe[dd] += me[c] * E; fe[c] += me[dd] * E;
      fr[dd] += mr[c] * E; fr[c] += mr[dd] * E;
    }
  }
  {
    float2* Lpe = (float2*)(L + (size_t)p * 10);
    float2* Lpr = (float2*)(L + (size_t)(p + NP) * 10);
#pragma unroll
    for (int i = 0; i < 5; i++) {
      float2 u, v;
      u.x = __logf(fmaxf(fe[2 * i], 1e-12f)) * en;
      u.y = __logf(fmaxf(fe[2 * i + 1], 1e-12f)) * en;
      v.x = __logf(fmaxf(fr[2 * i], 1e-12f)) * en;
      v.y = __logf(fmaxf(fr[2 * i + 1], 1e-12f)) * en;
      Lpe[i] = u; Lpr[i] = v;
    }
  }
}

// ---------------- final beliefs ----------------
__global__ __launch_bounds__(256) void k_beliefs(const float* __restrict__ logphi,
    const float* __restrict__ sum_in, const float* __restrict__ Rbuf, float* __restrict__ out) {
  int n = blockIdx.x * 256 + threadIdx.x;
  if (n >= NN) return;
  float alpha = Rbuf[100];
  float t[NC];
  float mx = -1e30f;
#pragma unroll
  for (int c = 0; c < NC; c++) {
    float v = logphi[n * NC + c] + alpha * sum_in[n * NC + c];
    t[c] = v;
    mx = fmaxf(mx, v);
  }
  float ssum = 0.f;
#pragma unroll
  for (int c = 0; c < NC; c++) { float ev = __expf(t[c] - mx); t[c] = ev; ssum += ev; }
  float inv = 1.f / ssum;
#pragma unroll
  for (int c = 0; c < NC; c++) out[(size_t)n * NC + c] = t[c] * inv;
}

extern "C" void kernel_launch(void* const* d_in, const int* in_sizes, int n_in,
                              void* d_out, int out_size, void* d_ws, size_t ws_size,
                              hipStream_t stream) {
  const float* x    = (const float*)d_in[0];
  const int*   ei   = (const int*)d_in[1];
  const float* ew1  = (const float*)d_in[3];
  const float* eb1  = (const float*)d_in[4];
  const float* ew2  = (const float*)d_in[5];
  const float* eb2  = (const float*)d_in[6];
  const float* mw1  = (const float*)d_in[7];
  const float* mb1  = (const float*)d_in[8];
  const float* mw2  = (const float*)d_in[9];
  const float* mb2  = (const float*)d_in[10];
  const float* Rraw = (const float*)d_in[11];
  const float* rsl  = (const float*)d_in[12];
  const float* ml   = (const float*)d_in[13];
  float* out = (float*)d_out;

  char* ws = (char*)d_ws;
  float* Rbuf   = (float*)(ws + OFF_R);
  f16*   h      = (f16*)(ws + OFF_H);
  int*   offs   = (int*)(ws + OFF_OFFS);
  int*   cursor = (int*)(ws + OFF_CUR);
  int*   csr    = (int*)(ws + OFF_CSR);
  int*   bsum   = (int*)(ws + OFF_BSUM);
  int*   bbase  = (int*)(ws + OFF_BBASE);
  float* logphi = (float*)(ws + OFF_LOGPHI);
  float* deg    = (float*)(ws + OFF_DEG);
  float* logdeg = (float*)(ws + OFF_LOGDEG);
  float* rsq    = (float*)(ws + OFF_RSQ);
  float* wpair  = (float*)(ws + OFF_WPAIR);
  float* enp    = (float*)(ws + OFF_EN);
  float* m      = (float*)(ws + OFF_M);
  float* L      = (float*)(ws + OFF_L);
  float* sumin  = (float*)(ws + OFF_SUMIN);
  f16*   w1t    = (f16*)(ws + OFF_W1T);

  k_setup<<<1, 256, 0, stream>>>(Rraw, rsl, ml, mw1, Rbuf, w1t);
  hipMemsetAsync(deg, 0, NN * sizeof(float), stream);
  k_deg<<<NEDGE / 256, 256, 0, stream>>>(ei, deg);
  k_nodepost<<<(NN + 255) / 256, 256, 0, stream>>>(deg, logdeg, rsq);
  k_encoder<<<(NN + 31) / 32, 256, 0, stream>>>(x, ew1, eb1, h);
  k_logits<<<NN / 16, 256, 0, stream>>>(h, ew2, eb2, logphi);
  k_edge_mlp<<<512, 256, 0, stream>>>(h, ei, logdeg, rsq, w1t, mw1, mb1, mw2, mb2, wpair, enp);
  // CSR build (h region is dead from here on)
  k_scan1<<<SCAN_NB, 256, 0, stream>>>(deg, bsum);
  k_scan2<<<1, 256, 0, stream>>>(bsum, bbase);
  k_scan3<<<SCAN_NB, 256, 0, stream>>>(deg, bbase, offs, cursor);
  k_fill<<<NEDGE / 256, 256, 0, stream>>>(ei, cursor, csr);
  k_m0<<<NEDGE / 256, 256, 0, stream>>>(ei, logphi, m);
  k_bp_f<<<NEDGE / 256, 256, 0, stream>>>(m, wpair, enp, Rbuf, L);

  const int gblocks = (NN + 23) / 24;  // 4 waves/block * 6 nodes/wave
  const int fblocks = (NP + 255) / 256;
  for (int it = 0; it < TBP; it++) {
    k_gather<<<gblocks, 256, 0, stream>>>(L, csr, offs, sumin);
    k_bp_fused<<<fblocks, 256, 0, stream>>>(m, L, sumin, logphi, ei, wpair, enp, Rbuf);
  }
  k_gather<<<gblocks, 256, 0, stream>>>(L, csr, offs, sumin);
  k_beliefs<<<(NN + 255) / 256, 256, 0, stream>>>(logphi, sumin, Rbuf, out);
}

// Round 7
// 1084.002 us; speedup vs baseline: 1.1732x; 1.1732x over previous
//
#include <hip/hip_runtime.h>
#include <hip/hip_fp16.h>

#define NN 50000
#define NP 400000
#define NEDGE 800000
#define IND 256
#define HD 128
#define NC 10
#define TBP 10
#define SCAN_NB 196  // ceil(NN/256)

typedef _Float16 f16;
typedef _Float16 f16x2 __attribute__((ext_vector_type(2)));
typedef _Float16 f16x4 __attribute__((ext_vector_type(4)));
typedef _Float16 f16x8 __attribute__((ext_vector_type(8)));
typedef unsigned short u16x8 __attribute__((ext_vector_type(8)));
typedef float f32x4 __attribute__((ext_vector_type(4)));

// ---- workspace offsets (bytes) ----
static constexpr size_t OFF_R      = 0;          // 128 f32: R[100], [100]=alpha
static constexpr size_t OFF_H      = 512;        // h fp16 [NN][128] (dead after edge_mlp)
static constexpr size_t OFF_OFFS   = 512;            // CSR off int[NN+1]   (aliases h)
static constexpr size_t OFF_CUR    = 512 + 200016;   // CSR cursor int[NN]  (aliases h)
static constexpr size_t OFF_CSR    = 512 + 400032;   // CSR edge ids int[NEDGE] (aliases h)
static constexpr size_t OFF_BSUM   = 512 + 3600032;  // int[256] block sums (aliases h)
static constexpr size_t OFF_BBASE  = 512 + 3601056;  // int[256] block bases (aliases h)
static constexpr size_t OFF_LOGPHI = 12800512;   // [NN][10] f32
static constexpr size_t OFF_DEG    = 14800512;   // [NN] f32
static constexpr size_t OFF_LOGDEG = 15000512;   // [NN] f32
static constexpr size_t OFF_RSQ    = 15200512;   // [NN] f32
static constexpr size_t OFF_WPAIR  = 15400512;   // [NP] f32
static constexpr size_t OFF_EN     = 17000512;   // [NP] f32
static constexpr size_t OFF_M      = 18600512;   // m edge-major [NEDGE][10] f32 (32MB)
static constexpr size_t OFF_L      = 50600512;   // log_f edge-major [NEDGE][10] f16 (16MB)
static constexpr size_t OFF_SUMIN  = 82600512;   // [NN][10] f32
static constexpr size_t OFF_W1T    = 84600512;   // edge W1^T fp16 [64][256]
static constexpr size_t OFF_W1TE   = 84633280;   // enc W1^T fp16 [128][256]

// ---------------- setup: R matrix, alpha, W1 transposes ----------------
__global__ __launch_bounds__(256) void k_setup(const float* __restrict__ Rraw,
    const float* __restrict__ rsl, const float* __restrict__ ml,
    const float* __restrict__ mw1, const float* __restrict__ ew1,
    float* __restrict__ Rbuf, f16* __restrict__ w1t, f16* __restrict__ w1te) {
  int tid = threadIdx.x;
  if (tid < 100) {
    int c = tid / 10, d = tid % 10;
    float scale = log1pf(expf(rsl[0])) + 1e-6f;
    Rbuf[tid] = scale * tanhf(0.5f * (Rraw[c * 10 + d] + Rraw[d * 10 + c]));
  } else if (tid == 100) {
    Rbuf[100] = 1.5f * (1.f / (1.f + expf(-ml[0])));  // ALPHA_MAX*sigmoid*ALPHA_SCALE
  }
  for (int idx = tid; idx < 64 * 256; idx += 256) {
    int j = idx >> 8, k = idx & 255;
    w1t[idx] = (f16)mw1[k * 64 + j];
  }
  for (int idx = tid; idx < 128 * 256; idx += 256) {
    int j = idx >> 8, k = idx & 255;
    w1te[idx] = (f16)ew1[k * HD + j];
  }
}

// ---------------- degree / node post ----------------
__global__ __launch_bounds__(256) void k_deg(const int* __restrict__ ei, float* __restrict__ deg) {
  int e = blockIdx.x * 256 + threadIdx.x;
  if (e < NEDGE) atomicAdd(&deg[ei[e]], 1.f);
}

__global__ __launch_bounds__(256) void k_nodepost(const float* __restrict__ deg,
    float* __restrict__ logdeg, float* __restrict__ rsq) {
  int i = blockIdx.x * 256 + threadIdx.x;
  if (i >= NN) return;
  float d = deg[i];
  logdeg[i] = __logf(d + 1.f);
  rsq[i] = rsqrtf(fmaxf(d, 1.f));
}

// ---------------- CSR build: 3-phase hierarchical scan ----------------
__global__ __launch_bounds__(256) void k_scan1(const float* __restrict__ deg,
    int* __restrict__ bsum) {
  int idx = blockIdx.x * 256 + threadIdx.x;
  int v = (idx < NN) ? (int)deg[idx] : 0;
#pragma unroll
  for (int o = 32; o; o >>= 1) v += __shfl_down(v, o);
  __shared__ int wsum[4];
  if ((threadIdx.x & 63) == 0) wsum[threadIdx.x >> 6] = v;
  __syncthreads();
  if (threadIdx.x == 0) bsum[blockIdx.x] = wsum[0] + wsum[1] + wsum[2] + wsum[3];
}

__global__ __launch_bounds__(256) void k_scan2(const int* __restrict__ bsum,
    int* __restrict__ bbase) {
  __shared__ int s[256];
  int t = threadIdx.x;
  int orig = (t < SCAN_NB) ? bsum[t] : 0;
  s[t] = orig;
  __syncthreads();
  for (int d = 1; d < 256; d <<= 1) {
    int v = (t >= d) ? s[t - d] : 0;
    __syncthreads();
    s[t] += v;
    __syncthreads();
  }
  bbase[t] = s[t] - orig;  // exclusive
}

__global__ __launch_bounds__(256) void k_scan3(const float* __restrict__ deg,
    const int* __restrict__ bbase, int* __restrict__ off, int* __restrict__ cursor) {
  __shared__ int s[256];
  int t = threadIdx.x;
  int idx = blockIdx.x * 256 + t;
  int d = (idx < NN) ? (int)deg[idx] : 0;
  s[t] = d;
  __syncthreads();
  for (int k = 1; k < 256; k <<= 1) {
    int v = (t >= k) ? s[t - k] : 0;
    __syncthreads();
    s[t] += v;
    __syncthreads();
  }
  int base = bbase[blockIdx.x];
  int excl = base + s[t] - d;
  if (idx < NN) {
    off[idx] = excl;
    cursor[idx] = excl;
  }
  if (idx == NN - 1) off[NN] = excl + d;
}

__global__ __launch_bounds__(256) void k_fill(const int* __restrict__ ei,
    int* __restrict__ cursor, int* __restrict__ csr) {
  int e = blockIdx.x * 256 + threadIdx.x;
  if (e >= NEDGE) return;
  int d = ei[NEDGE + e];
  int pos = atomicAdd(&cursor[d], 1);
  csr[pos] = e;
}

// ---------------- encoder: h = relu(x @ W1 + b1) via MFMA f16 ----------------
// block = 256 thr = 4 waves; 64 rows/block; wave w covers cols [w*32, w*32+32)
__global__ __launch_bounds__(256) void k_encoder(const float* __restrict__ x,
    const f16* __restrict__ w1te, const float* __restrict__ b1, f16* __restrict__ h) {
  __shared__ f16 As[64 * 264];  // 33 KB, stride 264 f16
  const int tid = threadIdx.x;
  const int wid = tid >> 6;
  const int lane = tid & 63;
  const int l15 = lane & 15;
  const int lhi = lane >> 4;
  const int nb = blockIdx.x * 64;
  // stage x (f32 -> f16) into LDS
#pragma unroll
  for (int i = 0; i < 16; i++) {
    int fidx = tid + 256 * i;   // f32x4 quad index; 64 quads/row
    int row = fidx >> 6;
    int q = fidx & 63;
    f32x4 v = {0.f, 0.f, 0.f, 0.f};
    if (nb + row < NN) v = *(const f32x4*)(x + (size_t)(nb + row) * IND + q * 4);
    f16x4 o;
#pragma unroll
    for (int j = 0; j < 4; j++) o[j] = (f16)v[j];
    *(f16x4*)(&As[row * 264 + q * 4]) = o;
  }
  __syncthreads();
  // persistent B fragments: cols j = wid*32 + t*16 + l15, k = ks*32 + lhi*8
  f16x8 bfr[8][2];
#pragma unroll
  for (int ks = 0; ks < 8; ks++)
#pragma unroll
    for (int t = 0; t < 2; t++)
      bfr[ks][t] = *(const f16x8*)(w1te + (size_t)(wid * 32 + t * 16 + l15) * 256 + ks * 32 + lhi * 8);
  float b1v[2] = {b1[wid * 32 + l15], b1[wid * 32 + 16 + l15]};
  f32x4 acc[4][2] = {};
#pragma unroll
  for (int ks = 0; ks < 8; ks++) {
    f16x8 af[4];
#pragma unroll
    for (int rt = 0; rt < 4; rt++)
      af[rt] = *(const f16x8*)(&As[(rt * 16 + l15) * 264 + ks * 32 + lhi * 8]);
#pragma unroll
    for (int rt = 0; rt < 4; rt++)
#pragma unroll
      for (int t = 0; t < 2; t++)
        acc[rt][t] = __builtin_amdgcn_mfma_f32_16x16x32_f16(af[rt], bfr[ks][t], acc[rt][t], 0, 0, 0);
  }
  // epilogue: C/D row = lhi*4 + i, col = l15 (+16t)
#pragma unroll
  for (int rt = 0; rt < 4; rt++) {
#pragma unroll
    for (int t = 0; t < 2; t++) {
#pragma unroll
      for (int i = 0; i < 4; i++) {
        int row = nb + rt * 16 + lhi * 4 + i;
        if (row < NN)
          h[(size_t)row * HD + wid * 32 + t * 16 + l15] = (f16)fmaxf(acc[rt][t][i] + b1v[t], 0.f);
      }
    }
  }
}

// ---------------- logits + log_softmax(logits/1.5) ----------------
__global__ __launch_bounds__(256) void k_logits(const f16* __restrict__ h,
    const float* __restrict__ w2, const float* __restrict__ b2, float* __restrict__ logphi) {
  __shared__ float hs[16 * HD];
  __shared__ float lg[16 * NC];
  const int tid = threadIdx.x;
  const int nb = blockIdx.x * 16;
  for (int i = tid; i < 16 * HD / 8; i += 256) {
    f16x8 v = *(const f16x8*)(h + (size_t)nb * HD + i * 8);
#pragma unroll
    for (int u = 0; u < 8; u++) hs[i * 8 + u] = (float)v[u];
  }
  __syncthreads();
  if (tid < 160) {
    int n = tid / 10, c = tid % 10;
    float a = b2[c];
    for (int k = 0; k < HD; k++) a += hs[n * HD + k] * w2[k * NC + c];
    lg[n * NC + c] = a * (1.f / 1.5f);
  }
  __syncthreads();
  if (tid < 16) {
    float mx = -1e30f;
#pragma unroll
    for (int c = 0; c < NC; c++) mx = fmaxf(mx, lg[tid * NC + c]);
    float s = 0.f;
#pragma unroll
    for (int c = 0; c < NC; c++) s += __expf(lg[tid * NC + c] - mx);
    float lse = __logf(s) + mx;
#pragma unroll
    for (int c = 0; c < NC; c++)
      logphi[(size_t)(nb + tid) * NC + c] = lg[tid * NC + c] - lse;
  }
}

// ---------------- edge MLP (per undirected pair), MFMA f16 ----------------
__global__ __launch_bounds__(256) void k_edge_mlp(const f16* __restrict__ h,
    const int* __restrict__ ei, const float* __restrict__ logdeg, const float* __restrict__ rsq,
    const f16* __restrict__ w1t, const float* __restrict__ mw1, const float* __restrict__ mb1,
    const float* __restrict__ mw2, const float* __restrict__ mb2,
    float* __restrict__ w_pair, float* __restrict__ en_pair) {
  __shared__ f16 At[4][16 * 264];
  __shared__ float hidl[4][16 * 64];
  __shared__ float sfeat[4][2][16];
  const int tid = threadIdx.x;
  const int wid = tid >> 6;
  const int lane = tid & 63;
  const int l15 = lane & 15;
  const int lhi = lane >> 4;

  f16x8 bfr[8][4];
#pragma unroll
  for (int ks = 0; ks < 8; ks++)
#pragma unroll
    for (int t = 0; t < 4; t++)
      bfr[ks][t] = *(const f16x8*)(w1t + (size_t)(l15 + 16 * t) * 256 + ks * 32 + lhi * 8);

  float b1v[4], w256v[4], w257v[4];
#pragma unroll
  for (int t = 0; t < 4; t++) {
    b1v[t] = mb1[l15 + 16 * t];
    w256v[t] = mw1[256 * 64 + l15 + 16 * t];
    w257v[t] = mw1[257 * 64 + l15 + 16 * t];
  }
  float w2r[16];
#pragma unroll
  for (int jj = 0; jj < 16; jj++) w2r[jj] = mw2[lhi * 16 + jj];
  const float b2s = mb2[0];

  const int ntiles = NP / 64;  // 6250
  for (int tile = blockIdx.x; tile < ntiles; tile += gridDim.x) {
    const int pbase = tile * 64 + wid * 16;
#pragma unroll
    for (int rr = 0; rr < 4; rr++) {
      int r = rr * 4 + lhi;
      int p = pbase + r;
      int s = ei[p], d = ei[NEDGE + p];
      f16x8 hv = *(const f16x8*)(h + (size_t)s * HD + l15 * 8);
      f16x8 gv = *(const f16x8*)(h + (size_t)d * HD + l15 * 8);
      f16x8 pv = hv * gv;
      f16x8 qv = hv - gv;
      u16x8 qb = *(u16x8*)&qv;
#pragma unroll
      for (int u = 0; u < 8; u++) qb[u] &= 0x7FFF;
      qv = *(f16x8*)&qb;
      *(f16x8*)(&At[wid][r * 264 + l15 * 8]) = pv;
      *(f16x8*)(&At[wid][r * 264 + 128 + l15 * 8]) = qv;
    }
    if (lane < 16) {
      int p = pbase + lane;
      int s = ei[p], d = ei[NEDGE + p];
      float a = logdeg[s], b = logdeg[d];
      sfeat[wid][0][lane] = a + b;
      sfeat[wid][1][lane] = fabsf(a - b);
      en_pair[p] = rsq[s] * rsq[d];
    }
    __syncthreads();
    f32x4 acc[4] = {{0.f, 0.f, 0.f, 0.f}, {0.f, 0.f, 0.f, 0.f},
                    {0.f, 0.f, 0.f, 0.f}, {0.f, 0.f, 0.f, 0.f}};
#pragma unroll
    for (int ks = 0; ks < 8; ks++) {
      f16x8 af = *(const f16x8*)(&At[wid][l15 * 264 + ks * 32 + lhi * 8]);
#pragma unroll
      for (int t = 0; t < 4; t++)
        acc[t] = __builtin_amdgcn_mfma_f32_16x16x32_f16(af, bfr[ks][t], acc[t], 0, 0, 0);
    }
#pragma unroll
    for (int t = 0; t < 4; t++) {
#pragma unroll
      for (int i = 0; i < 4; i++) {
        int r = lhi * 4 + i;
        float v = acc[t][i] + sfeat[wid][0][r] * w256v[t] + sfeat[wid][1][r] * w257v[t] + b1v[t];
        hidl[wid][r * 64 + l15 + 16 * t] = fmaxf(v, 0.f);
      }
    }
    __syncthreads();
    {
      float sacc = 0.f;
#pragma unroll
      for (int jj = 0; jj < 16; jj++) sacc += hidl[wid][l15 * 64 + lhi * 16 + jj] * w2r[jj];
      sacc += __shfl_xor(sacc, 16);
      sacc += __shfl_xor(sacc, 32);
      if (lane < 16) {
        float wr = sacc + b2s;
        w_pair[pbase + lane] = 0.8f / (1.f + __expf(-wr));
      }
    }
    __syncthreads();
  }
}

// ---------------- m0 = exp(log_phi[src]) (edge-major) ----------------
__global__ __launch_bounds__(256) void k_m0(const int* __restrict__ ei,
    const float* __restrict__ logphi, float* __restrict__ m) {
  int e = blockIdx.x * 256 + threadIdx.x;
  if (e >= NEDGE) return;
  int s = ei[e];
  float2* mp = (float2*)(m + (size_t)e * 10);
  const float2* lp = (const float2*)(logphi + (size_t)s * 10);
#pragma unroll
  for (int i = 0; i < 5; i++) {
    float2 v = lp[i];
    float2 o;
    o.x = __expf(v.x);
    o.y = __expf(v.y);
    mp[i] = o;
  }
}

// ---------------- initial L: f from m0 (per directed edge) ----------------
__global__ __launch_bounds__(256) void k_bp_f(const float* __restrict__ m,
    const float* __restrict__ wp, const float* __restrict__ enp,
    const float* __restrict__ Rbuf, f16* __restrict__ L) {
  __shared__ float Rs[100];
  if (threadIdx.x < 100) Rs[threadIdx.x] = Rbuf[threadIdx.x];
  __syncthreads();
  int e = blockIdx.x * 256 + threadIdx.x;
  if (e >= NEDGE) return;
  int p = (e < NP) ? e : e - NP;
  float w = wp[p], en = enp[p];
  float mr[10];
  {
    const float2* mp = (const float2*)(m + (size_t)e * 10);
#pragma unroll
    for (int i = 0; i < 5; i++) { float2 v = mp[i]; mr[2 * i] = v.x; mr[2 * i + 1] = v.y; }
  }
  float f[10] = {0, 0, 0, 0, 0, 0, 0, 0, 0, 0};
#pragma unroll
  for (int c = 0; c < NC; c++) {
    float Ecc = __expf(w * Rs[c * NC + c]);
    f[c] += mr[c] * Ecc;
#pragma unroll
    for (int d = c + 1; d < NC; d++) {
      float Ecd = __expf(w * Rs[c * NC + d]);
      f[d] += mr[c] * Ecd;
      f[c] += mr[d] * Ecd;
    }
  }
  f16x2* Lp = (f16x2*)(L + (size_t)e * 10);
#pragma unroll
  for (int i = 0; i < 5; i++) {
    f16x2 o;
    o[0] = (f16)(__logf(fmaxf(f[2 * i], 1e-12f)) * en);
    o[1] = (f16)(__logf(fmaxf(f[2 * i + 1], 1e-12f)) * en);
    Lp[i] = o;
  }
}

// ---------------- gather segment-reduce: sum_in[n][c] = sum L[incoming][c] ----------------
__global__ __launch_bounds__(256) void k_gather(const f16* __restrict__ L,
    const int* __restrict__ csr, const int* __restrict__ off, float* __restrict__ sumin) {
  int wave = (blockIdx.x * 256 + threadIdx.x) >> 6;
  int lane = threadIdx.x & 63;
  int nl = lane / 10;   // 0..5 (6 nodes per wave), lanes 60..63 idle
  int c = lane % 10;
  int n = wave * 6 + nl;
  if (nl >= 6 || n >= NN) return;
  int o0 = off[n], o1 = off[n + 1];
  float acc = 0.f;
  for (int k = o0; k < o1; k++) {
    int e = csr[k];
    acc += (float)L[(size_t)e * 10 + c];
  }
  sumin[(size_t)n * 10 + c] = acc;
}

// ---------------- fused BP step (per undirected pair): upd both dirs + new L ----------------
__global__ __launch_bounds__(256) void k_bp_fused(float* __restrict__ m,
    f16* __restrict__ L, const float* __restrict__ sumin,
    const float* __restrict__ logphi, const int* __restrict__ ei,
    const float* __restrict__ wp, const float* __restrict__ enp,
    const float* __restrict__ Rbuf) {
  __shared__ float Rs[104];
  if (threadIdx.x < 101) Rs[threadIdx.x] = Rbuf[threadIdx.x];
  __syncthreads();
  int p = blockIdx.x * 256 + threadIdx.x;
  if (p >= NP) return;
  const float alpha = Rs[100];
  const int s = ei[p], d = ei[NEDGE + p];
  const float w = wp[p], en = enp[p];

  float Le[10], Lr[10];
  {
    const f16x2* a = (const f16x2*)(L + (size_t)p * 10);
    const f16x2* b = (const f16x2*)(L + (size_t)(p + NP) * 10);
#pragma unroll
    for (int i = 0; i < 5; i++) {
      f16x2 u = a[i], v = b[i];
      Le[2 * i] = (float)u[0]; Le[2 * i + 1] = (float)u[1];
      Lr[2 * i] = (float)v[0]; Lr[2 * i + 1] = (float)v[1];
    }
  }
  float te[10], tr[10];
  float mxe = -1e30f, mxr = -1e30f;
  {
    const float2* sis = (const float2*)(sumin + (size_t)s * 10);
    const float2* sid = (const float2*)(sumin + (size_t)d * 10);
    const float2* lps = (const float2*)(logphi + (size_t)s * 10);
    const float2* lpd = (const float2*)(logphi + (size_t)d * 10);
#pragma unroll
    for (int i = 0; i < 5; i++) {
      float2 ss = sis[i], sd = sid[i], ps = lps[i], pd = lpd[i];
      float e0 = ps.x + alpha * (ss.x - Lr[2 * i]);
      float e1 = ps.y + alpha * (ss.y - Lr[2 * i + 1]);
      float r0 = pd.x + alpha * (sd.x - Le[2 * i]);
      float r1 = pd.y + alpha * (sd.y - Le[2 * i + 1]);
      te[2 * i] = e0; te[2 * i + 1] = e1;
      tr[2 * i] = r0; tr[2 * i + 1] = r1;
      mxe = fmaxf(mxe, fmaxf(e0, e1));
      mxr = fmaxf(mxr, fmaxf(r0, r1));
    }
  }
  float se = 0.f, sr = 0.f;
#pragma unroll
  for (int c = 0; c < NC; c++) {
    float ve = __expf(te[c] - mxe);
    float vr = __expf(tr[c] - mxr);
    te[c] = ve; tr[c] = vr;
    se += ve; sr += vr;
  }
  const float ie = 0.2f / se, ir = 0.2f / sr;
  float me[10], mr[10];
  float nse = 0.f, nsr = 0.f;
  {
    float2* mpe = (float2*)(m + (size_t)p * 10);
    float2* mpr = (float2*)(m + (size_t)(p + NP) * 10);
#pragma unroll
    for (int i = 0; i < 5; i++) {
      float2 u = mpe[i], v = mpr[i];
      float a0 = fmaxf(0.8f * u.x + te[2 * i] * ie, 1e-12f);
      float a1 = fmaxf(0.8f * u.y + te[2 * i + 1] * ie, 1e-12f);
      float b0 = fmaxf(0.8f * v.x + tr[2 * i] * ir, 1e-12f);
      float b1 = fmaxf(0.8f * v.y + tr[2 * i + 1] * ir, 1e-12f);
      me[2 * i] = a0; me[2 * i + 1] = a1;
      mr[2 * i] = b0; mr[2 * i + 1] = b1;
      nse += a0 + a1; nsr += b0 + b1;
    }
    const float qe = 1.f / nse, qr = 1.f / nsr;
#pragma unroll
    for (int i = 0; i < 5; i++) {
      float2 u, v;
      u.x = me[2 * i] * qe; u.y = me[2 * i + 1] * qe;
      v.x = mr[2 * i] * qr; v.y = mr[2 * i + 1] * qr;
      me[2 * i] = u.x; me[2 * i + 1] = u.y;
      mr[2 * i] = v.x; mr[2 * i + 1] = v.y;
      mpe[i] = u; mpr[i] = v;
    }
  }
  float fe[10] = {0, 0, 0, 0, 0, 0, 0, 0, 0, 0};
  float fr[10] = {0, 0, 0, 0, 0, 0, 0, 0, 0, 0};
#pragma unroll
  for (int c = 0; c < NC; c++) {
    float Ecc = __expf(w * Rs[c * NC + c]);
    fe[c] += me[c] * Ecc;
    fr[c] += mr[c] * Ecc;
#pragma unroll
    for (int dd = c + 1; dd < NC; dd++) {
      float E = __expf(w * Rs[c * NC + dd]);
      fe[dd] += me[c] * E; fe[c] += me[dd] * E;
      fr[dd] += mr[c] * E; fr[c] += mr[dd] * E;
    }
  }
  {
    f16x2* Lpe = (f16x2*)(L + (size_t)p * 10);
    f16x2* Lpr = (f16x2*)(L + (size_t)(p + NP) * 10);
#pragma unroll
    for (int i = 0; i < 5; i++) {
      f16x2 u, v;
      u[0] = (f16)(__logf(fmaxf(fe[2 * i], 1e-12f)) * en);
      u[1] = (f16)(__logf(fmaxf(fe[2 * i + 1], 1e-12f)) * en);
      v[0] = (f16)(__logf(fmaxf(fr[2 * i], 1e-12f)) * en);
      v[1] = (f16)(__logf(fmaxf(fr[2 * i + 1], 1e-12f)) * en);
      Lpe[i] = u; Lpr[i] = v;
    }
  }
}

// ---------------- final beliefs ----------------
__global__ __launch_bounds__(256) void k_beliefs(const float* __restrict__ logphi,
    const float* __restrict__ sum_in, const float* __restrict__ Rbuf, float* __restrict__ out) {
  int n = blockIdx.x * 256 + threadIdx.x;
  if (n >= NN) return;
  float alpha = Rbuf[100];
  float t[NC];
  float mx = -1e30f;
#pragma unroll
  for (int c = 0; c < NC; c++) {
    float v = logphi[n * NC + c] + alpha * sum_in[n * NC + c];
    t[c] = v;
    mx = fmaxf(mx, v);
  }
  float ssum = 0.f;
#pragma unroll
  for (int c = 0; c < NC; c++) { float ev = __expf(t[c] - mx); t[c] = ev; ssum += ev; }
  float inv = 1.f / ssum;
#pragma unroll
  for (int c = 0; c < NC; c++) out[(size_t)n * NC + c] = t[c] * inv;
}

extern "C" void kernel_launch(void* const* d_in, const int* in_sizes, int n_in,
                              void* d_out, int out_size, void* d_ws, size_t ws_size,
                              hipStream_t stream) {
  const float* x    = (const float*)d_in[0];
  const int*   ei   = (const int*)d_in[1];
  const float* ew1  = (const float*)d_in[3];
  const float* eb1  = (const float*)d_in[4];
  const float* ew2  = (const float*)d_in[5];
  const float* eb2  = (const float*)d_in[6];
  const float* mw1  = (const float*)d_in[7];
  const float* mb1  = (const float*)d_in[8];
  const float* mw2  = (const float*)d_in[9];
  const float* mb2  = (const float*)d_in[10];
  const float* Rraw = (const float*)d_in[11];
  const float* rsl  = (const float*)d_in[12];
  const float* ml   = (const float*)d_in[13];
  float* out = (float*)d_out;

  char* ws = (char*)d_ws;
  float* Rbuf   = (float*)(ws + OFF_R);
  f16*   h      = (f16*)(ws + OFF_H);
  int*   offs   = (int*)(ws + OFF_OFFS);
  int*   cursor = (int*)(ws + OFF_CUR);
  int*   csr    = (int*)(ws + OFF_CSR);
  int*   bsum   = (int*)(ws + OFF_BSUM);
  int*   bbase  = (int*)(ws + OFF_BBASE);
  float* logphi = (float*)(ws + OFF_LOGPHI);
  float* deg    = (float*)(ws + OFF_DEG);
  float* logdeg = (float*)(ws + OFF_LOGDEG);
  float* rsq    = (float*)(ws + OFF_RSQ);
  float* wpair  = (float*)(ws + OFF_WPAIR);
  float* enp    = (float*)(ws + OFF_EN);
  float* m      = (float*)(ws + OFF_M);
  f16*   L      = (f16*)(ws + OFF_L);
  float* sumin  = (float*)(ws + OFF_SUMIN);
  f16*   w1t    = (f16*)(ws + OFF_W1T);
  f16*   w1te   = (f16*)(ws + OFF_W1TE);

  k_setup<<<1, 256, 0, stream>>>(Rraw, rsl, ml, mw1, ew1, Rbuf, w1t, w1te);
  hipMemsetAsync(deg, 0, NN * sizeof(float), stream);
  k_deg<<<NEDGE / 256, 256, 0, stream>>>(ei, deg);
  k_nodepost<<<(NN + 255) / 256, 256, 0, stream>>>(deg, logdeg, rsq);
  k_encoder<<<(NN + 63) / 64, 256, 0, stream>>>(x, w1te, eb1, h);
  k_logits<<<NN / 16, 256, 0, stream>>>(h, ew2, eb2, logphi);
  k_edge_mlp<<<512, 256, 0, stream>>>(h, ei, logdeg, rsq, w1t, mw1, mb1, mw2, mb2, wpair, enp);
  // CSR build (h region is dead from here on)
  k_scan1<<<SCAN_NB, 256, 0, stream>>>(deg, bsum);
  k_scan2<<<1, 256, 0, stream>>>(bsum, bbase);
  k_scan3<<<SCAN_NB, 256, 0, stream>>>(deg, bbase, offs, cursor);
  k_fill<<<NEDGE / 256, 256, 0, stream>>>(ei, cursor, csr);
  k_m0<<<NEDGE / 256, 256, 0, stream>>>(ei, logphi, m);
  k_bp_f<<<NEDGE / 256, 256, 0, stream>>>(m, wpair, enp, Rbuf, L);

  const int gblocks = (NN + 23) / 24;  // 4 waves/block * 6 nodes/wave
  const int fblocks = (NP + 255) / 256;
  for (int it = 0; it < TBP; it++) {
    k_gather<<<gblocks, 256, 0, stream>>>(L, csr, offs, sumin);
    k_bp_fused<<<fblocks, 256, 0, stream>>>(m, L, sumin, logphi, ei, wpair, enp, Rbuf);
  }
  k_gather<<<gblocks, 256, 0, stream>>>(L, csr, offs, sumin);
  k_beliefs<<<(NN + 255) / 256, 256, 0, stream>>>(logphi, sumin, Rbuf, out);
}

// Round 8
// 1076.393 us; speedup vs baseline: 1.1815x; 1.0071x over previous
//
#include <hip/hip_runtime.h>
#include <hip/hip_fp16.h>

#define NN 50000
#define NP 400000
#define NEDGE 800000
#define IND 256
#define HD 128
#define NC 10
#define TBP 10
#define SCAN_NB 196  // ceil(NN/256)

typedef _Float16 f16;
typedef _Float16 f16x2 __attribute__((ext_vector_type(2)));
typedef _Float16 f16x4 __attribute__((ext_vector_type(4)));
typedef _Float16 f16x8 __attribute__((ext_vector_type(8)));
typedef unsigned short u16x8 __attribute__((ext_vector_type(8)));
typedef float f32x4 __attribute__((ext_vector_type(4)));

// ---- workspace offsets (bytes) ----
static constexpr size_t OFF_R      = 0;          // 128 f32: R[100], [100]=alpha
static constexpr size_t OFF_H      = 512;        // h fp16 [NN][128] (dead after edge_mlp)
static constexpr size_t OFF_OFFS   = 512;            // CSR off int[NN+1]   (aliases h)
static constexpr size_t OFF_CUR    = 512 + 200016;   // CSR cursor int[NN]  (aliases h)
static constexpr size_t OFF_POS    = 512 + 400032;   // pos int[NEDGE]: edge -> CSR slot (aliases h)
static constexpr size_t OFF_BSUM   = 512 + 3600032;  // int[256] block sums (aliases h)
static constexpr size_t OFF_BBASE  = 512 + 3601056;  // int[256] block bases (aliases h)
static constexpr size_t OFF_LOGPHI = 12800512;   // [NN][10] f32
static constexpr size_t OFF_DEG    = 14800512;   // [NN] f32
static constexpr size_t OFF_LOGDEG = 15000512;   // [NN] f32
static constexpr size_t OFF_RSQ    = 15200512;   // [NN] f32
static constexpr size_t OFF_WPAIR  = 15400512;   // [NP] f32
static constexpr size_t OFF_EN     = 17000512;   // [NP] f32
static constexpr size_t OFF_M      = 18600512;   // m edge-major [NEDGE][10] f16 (16MB)
static constexpr size_t OFF_L      = 50600512;   // L CSR-ordered [NEDGE][10] f16 (16MB)
static constexpr size_t OFF_SUMIN  = 82600512;   // [NN][10] f32
static constexpr size_t OFF_W1T    = 84600512;   // edge W1^T fp16 [64][256]
static constexpr size_t OFF_W1TE   = 84633280;   // enc W1^T fp16 [128][256]

// ---------------- setup: R matrix, alpha, W1 transposes ----------------
__global__ __launch_bounds__(256) void k_setup(const float* __restrict__ Rraw,
    const float* __restrict__ rsl, const float* __restrict__ ml,
    const float* __restrict__ mw1, const float* __restrict__ ew1,
    float* __restrict__ Rbuf, f16* __restrict__ w1t, f16* __restrict__ w1te) {
  int tid = threadIdx.x;
  if (tid < 100) {
    int c = tid / 10, d = tid % 10;
    float scale = log1pf(expf(rsl[0])) + 1e-6f;
    Rbuf[tid] = scale * tanhf(0.5f * (Rraw[c * 10 + d] + Rraw[d * 10 + c]));
  } else if (tid == 100) {
    Rbuf[100] = 1.5f * (1.f / (1.f + expf(-ml[0])));  // ALPHA_MAX*sigmoid*ALPHA_SCALE
  }
  for (int idx = tid; idx < 64 * 256; idx += 256) {
    int j = idx >> 8, k = idx & 255;
    w1t[idx] = (f16)mw1[k * 64 + j];
  }
  for (int idx = tid; idx < 128 * 256; idx += 256) {
    int j = idx >> 8, k = idx & 255;
    w1te[idx] = (f16)ew1[k * HD + j];
  }
}

// ---------------- degree / node post ----------------
__global__ __launch_bounds__(256) void k_deg(const int* __restrict__ ei, float* __restrict__ deg) {
  int e = blockIdx.x * 256 + threadIdx.x;
  if (e < NEDGE) atomicAdd(&deg[ei[e]], 1.f);
}

__global__ __launch_bounds__(256) void k_nodepost(const float* __restrict__ deg,
    float* __restrict__ logdeg, float* __restrict__ rsq) {
  int i = blockIdx.x * 256 + threadIdx.x;
  if (i >= NN) return;
  float d = deg[i];
  logdeg[i] = __logf(d + 1.f);
  rsq[i] = rsqrtf(fmaxf(d, 1.f));
}

// ---------------- CSR build: 3-phase hierarchical scan ----------------
__global__ __launch_bounds__(256) void k_scan1(const float* __restrict__ deg,
    int* __restrict__ bsum) {
  int idx = blockIdx.x * 256 + threadIdx.x;
  int v = (idx < NN) ? (int)deg[idx] : 0;
#pragma unroll
  for (int o = 32; o; o >>= 1) v += __shfl_down(v, o);
  __shared__ int wsum[4];
  if ((threadIdx.x & 63) == 0) wsum[threadIdx.x >> 6] = v;
  __syncthreads();
  if (threadIdx.x == 0) bsum[blockIdx.x] = wsum[0] + wsum[1] + wsum[2] + wsum[3];
}

__global__ __launch_bounds__(256) void k_scan2(const int* __restrict__ bsum,
    int* __restrict__ bbase) {
  __shared__ int s[256];
  int t = threadIdx.x;
  int orig = (t < SCAN_NB) ? bsum[t] : 0;
  s[t] = orig;
  __syncthreads();
  for (int d = 1; d < 256; d <<= 1) {
    int v = (t >= d) ? s[t - d] : 0;
    __syncthreads();
    s[t] += v;
    __syncthreads();
  }
  bbase[t] = s[t] - orig;  // exclusive
}

__global__ __launch_bounds__(256) void k_scan3(const float* __restrict__ deg,
    const int* __restrict__ bbase, int* __restrict__ off, int* __restrict__ cursor) {
  __shared__ int s[256];
  int t = threadIdx.x;
  int idx = blockIdx.x * 256 + t;
  int d = (idx < NN) ? (int)deg[idx] : 0;
  s[t] = d;
  __syncthreads();
  for (int k = 1; k < 256; k <<= 1) {
    int v = (t >= k) ? s[t - k] : 0;
    __syncthreads();
    s[t] += v;
    __syncthreads();
  }
  int base = bbase[blockIdx.x];
  int excl = base + s[t] - d;
  if (idx < NN) {
    off[idx] = excl;
    cursor[idx] = excl;
  }
  if (idx == NN - 1) off[NN] = excl + d;
}

// fill: pos[e] = slot in dst-sorted order (coalesced write; no scattered csr)
__global__ __launch_bounds__(256) void k_fill(const int* __restrict__ ei,
    int* __restrict__ cursor, int* __restrict__ pos) {
  int e = blockIdx.x * 256 + threadIdx.x;
  if (e >= NEDGE) return;
  int d = ei[NEDGE + e];
  pos[e] = atomicAdd(&cursor[d], 1);
}

// ---------------- encoder: h = relu(x @ W1 + b1) via MFMA f16 ----------------
__global__ __launch_bounds__(256) void k_encoder(const float* __restrict__ x,
    const f16* __restrict__ w1te, const float* __restrict__ b1, f16* __restrict__ h) {
  __shared__ f16 As[64 * 264];
  const int tid = threadIdx.x;
  const int wid = tid >> 6;
  const int lane = tid & 63;
  const int l15 = lane & 15;
  const int lhi = lane >> 4;
  const int nb = blockIdx.x * 64;
#pragma unroll
  for (int i = 0; i < 16; i++) {
    int fidx = tid + 256 * i;
    int row = fidx >> 6;
    int q = fidx & 63;
    f32x4 v = {0.f, 0.f, 0.f, 0.f};
    if (nb + row < NN) v = *(const f32x4*)(x + (size_t)(nb + row) * IND + q * 4);
    f16x4 o;
#pragma unroll
    for (int j = 0; j < 4; j++) o[j] = (f16)v[j];
    *(f16x4*)(&As[row * 264 + q * 4]) = o;
  }
  __syncthreads();
  f16x8 bfr[8][2];
#pragma unroll
  for (int ks = 0; ks < 8; ks++)
#pragma unroll
    for (int t = 0; t < 2; t++)
      bfr[ks][t] = *(const f16x8*)(w1te + (size_t)(wid * 32 + t * 16 + l15) * 256 + ks * 32 + lhi * 8);
  float b1v[2] = {b1[wid * 32 + l15], b1[wid * 32 + 16 + l15]};
  f32x4 acc[4][2] = {};
#pragma unroll
  for (int ks = 0; ks < 8; ks++) {
    f16x8 af[4];
#pragma unroll
    for (int rt = 0; rt < 4; rt++)
      af[rt] = *(const f16x8*)(&As[(rt * 16 + l15) * 264 + ks * 32 + lhi * 8]);
#pragma unroll
    for (int rt = 0; rt < 4; rt++)
#pragma unroll
      for (int t = 0; t < 2; t++)
        acc[rt][t] = __builtin_amdgcn_mfma_f32_16x16x32_f16(af[rt], bfr[ks][t], acc[rt][t], 0, 0, 0);
  }
#pragma unroll
  for (int rt = 0; rt < 4; rt++) {
#pragma unroll
    for (int t = 0; t < 2; t++) {
#pragma unroll
      for (int i = 0; i < 4; i++) {
        int row = nb + rt * 16 + lhi * 4 + i;
        if (row < NN)
          h[(size_t)row * HD + wid * 32 + t * 16 + l15] = (f16)fmaxf(acc[rt][t][i] + b1v[t], 0.f);
      }
    }
  }
}

// ---------------- logits + log_softmax(logits/1.5) ----------------
__global__ __launch_bounds__(256) void k_logits(const f16* __restrict__ h,
    const float* __restrict__ w2, const float* __restrict__ b2, float* __restrict__ logphi) {
  __shared__ float hs[16 * HD];
  __shared__ float lg[16 * NC];
  const int tid = threadIdx.x;
  const int nb = blockIdx.x * 16;
  for (int i = tid; i < 16 * HD / 8; i += 256) {
    f16x8 v = *(const f16x8*)(h + (size_t)nb * HD + i * 8);
#pragma unroll
    for (int u = 0; u < 8; u++) hs[i * 8 + u] = (float)v[u];
  }
  __syncthreads();
  if (tid < 160) {
    int n = tid / 10, c = tid % 10;
    float a = b2[c];
    for (int k = 0; k < HD; k++) a += hs[n * HD + k] * w2[k * NC + c];
    lg[n * NC + c] = a * (1.f / 1.5f);
  }
  __syncthreads();
  if (tid < 16) {
    float mx = -1e30f;
#pragma unroll
    for (int c = 0; c < NC; c++) mx = fmaxf(mx, lg[tid * NC + c]);
    float s = 0.f;
#pragma unroll
    for (int c = 0; c < NC; c++) s += __expf(lg[tid * NC + c] - mx);
    float lse = __logf(s) + mx;
#pragma unroll
    for (int c = 0; c < NC; c++)
      logphi[(size_t)(nb + tid) * NC + c] = lg[tid * NC + c] - lse;
  }
}

// ---------------- edge MLP (per undirected pair), MFMA f16 ----------------
__global__ __launch_bounds__(256) void k_edge_mlp(const f16* __restrict__ h,
    const int* __restrict__ ei, const float* __restrict__ logdeg, const float* __restrict__ rsq,
    const f16* __restrict__ w1t, const float* __restrict__ mw1, const float* __restrict__ mb1,
    const float* __restrict__ mw2, const float* __restrict__ mb2,
    float* __restrict__ w_pair, float* __restrict__ en_pair) {
  __shared__ f16 At[4][16 * 264];
  __shared__ float hidl[4][16 * 64];
  __shared__ float sfeat[4][2][16];
  const int tid = threadIdx.x;
  const int wid = tid >> 6;
  const int lane = tid & 63;
  const int l15 = lane & 15;
  const int lhi = lane >> 4;

  f16x8 bfr[8][4];
#pragma unroll
  for (int ks = 0; ks < 8; ks++)
#pragma unroll
    for (int t = 0; t < 4; t++)
      bfr[ks][t] = *(const f16x8*)(w1t + (size_t)(l15 + 16 * t) * 256 + ks * 32 + lhi * 8);

  float b1v[4], w256v[4], w257v[4];
#pragma unroll
  for (int t = 0; t < 4; t++) {
    b1v[t] = mb1[l15 + 16 * t];
    w256v[t] = mw1[256 * 64 + l15 + 16 * t];
    w257v[t] = mw1[257 * 64 + l15 + 16 * t];
  }
  float w2r[16];
#pragma unroll
  for (int jj = 0; jj < 16; jj++) w2r[jj] = mw2[lhi * 16 + jj];
  const float b2s = mb2[0];

  const int ntiles = NP / 64;  // 6250
  for (int tile = blockIdx.x; tile < ntiles; tile += gridDim.x) {
    const int pbase = tile * 64 + wid * 16;
#pragma unroll
    for (int rr = 0; rr < 4; rr++) {
      int r = rr * 4 + lhi;
      int p = pbase + r;
      int s = ei[p], d = ei[NEDGE + p];
      f16x8 hv = *(const f16x8*)(h + (size_t)s * HD + l15 * 8);
      f16x8 gv = *(const f16x8*)(h + (size_t)d * HD + l15 * 8);
      f16x8 pv = hv * gv;
      f16x8 qv = hv - gv;
      u16x8 qb = *(u16x8*)&qv;
#pragma unroll
      for (int u = 0; u < 8; u++) qb[u] &= 0x7FFF;
      qv = *(f16x8*)&qb;
      *(f16x8*)(&At[wid][r * 264 + l15 * 8]) = pv;
      *(f16x8*)(&At[wid][r * 264 + 128 + l15 * 8]) = qv;
    }
    if (lane < 16) {
      int p = pbase + lane;
      int s = ei[p], d = ei[NEDGE + p];
      float a = logdeg[s], b = logdeg[d];
      sfeat[wid][0][lane] = a + b;
      sfeat[wid][1][lane] = fabsf(a - b);
      en_pair[p] = rsq[s] * rsq[d];
    }
    __syncthreads();
    f32x4 acc[4] = {{0.f, 0.f, 0.f, 0.f}, {0.f, 0.f, 0.f, 0.f},
                    {0.f, 0.f, 0.f, 0.f}, {0.f, 0.f, 0.f, 0.f}};
#pragma unroll
    for (int ks = 0; ks < 8; ks++) {
      f16x8 af = *(const f16x8*)(&At[wid][l15 * 264 + ks * 32 + lhi * 8]);
#pragma unroll
      for (int t = 0; t < 4; t++)
        acc[t] = __builtin_amdgcn_mfma_f32_16x16x32_f16(af, bfr[ks][t], acc[t], 0, 0, 0);
    }
#pragma unroll
    for (int t = 0; t < 4; t++) {
#pragma unroll
      for (int i = 0; i < 4; i++) {
        int r = lhi * 4 + i;
        float v = acc[t][i] + sfeat[wid][0][r] * w256v[t] + sfeat[wid][1][r] * w257v[t] + b1v[t];
        hidl[wid][r * 64 + l15 + 16 * t] = fmaxf(v, 0.f);
      }
    }
    __syncthreads();
    {
      float sacc = 0.f;
#pragma unroll
      for (int jj = 0; jj < 16; jj++) sacc += hidl[wid][l15 * 64 + lhi * 16 + jj] * w2r[jj];
      sacc += __shfl_xor(sacc, 16);
      sacc += __shfl_xor(sacc, 32);
      if (lane < 16) {
        float wr = sacc + b2s;
        w_pair[pbase + lane] = 0.8f / (1.f + __expf(-wr));
      }
    }
    __syncthreads();
  }
}

// ---------------- m0 = exp(log_phi[src]) (edge-major, f16) ----------------
__global__ __launch_bounds__(256) void k_m0(const int* __restrict__ ei,
    const float* __restrict__ logphi, f16* __restrict__ m) {
  int e = blockIdx.x * 256 + threadIdx.x;
  if (e >= NEDGE) return;
  int s = ei[e];
  f16x2* mp = (f16x2*)(m + (size_t)e * 10);
  const float2* lp = (const float2*)(logphi + (size_t)s * 10);
#pragma unroll
  for (int i = 0; i < 5; i++) {
    float2 v = lp[i];
    f16x2 o;
    o[0] = (f16)__expf(v.x);
    o[1] = (f16)__expf(v.y);
    mp[i] = o;
  }
}

// ---------------- initial L (CSR-ordered) from m0 ----------------
__global__ __launch_bounds__(256) void k_bp_f(const f16* __restrict__ m,
    const float* __restrict__ wp, const float* __restrict__ enp,
    const int* __restrict__ pos, const float* __restrict__ Rbuf, f16* __restrict__ L) {
  __shared__ float Rs[100];
  if (threadIdx.x < 100) Rs[threadIdx.x] = Rbuf[threadIdx.x];
  __syncthreads();
  int e = blockIdx.x * 256 + threadIdx.x;
  if (e >= NEDGE) return;
  int p = (e < NP) ? e : e - NP;
  float w = wp[p], en = enp[p];
  float mr[10];
  {
    const f16x2* mp = (const f16x2*)(m + (size_t)e * 10);
#pragma unroll
    for (int i = 0; i < 5; i++) { f16x2 v = mp[i]; mr[2 * i] = (float)v[0]; mr[2 * i + 1] = (float)v[1]; }
  }
  float f[10] = {0, 0, 0, 0, 0, 0, 0, 0, 0, 0};
#pragma unroll
  for (int c = 0; c < NC; c++) {
    float Ecc = __expf(w * Rs[c * NC + c]);
    f[c] += mr[c] * Ecc;
#pragma unroll
    for (int d = c + 1; d < NC; d++) {
      float Ecd = __expf(w * Rs[c * NC + d]);
      f[d] += mr[c] * Ecd;
      f[c] += mr[d] * Ecd;
    }
  }
  f16x2* Lp = (f16x2*)(L + (size_t)pos[e] * 10);
#pragma unroll
  for (int i = 0; i < 5; i++) {
    f16x2 o;
    o[0] = (f16)(__logf(fmaxf(f[2 * i], 1e-12f)) * en);
    o[1] = (f16)(__logf(fmaxf(f[2 * i + 1], 1e-12f)) * en);
    Lp[i] = o;
  }
}

// ---------------- gather: sum_in[n][c] = sum of contiguous CSR rows ----------------
__global__ __launch_bounds__(256) void k_gather(const f16* __restrict__ L,
    const int* __restrict__ off, float* __restrict__ sumin) {
  int wave = (blockIdx.x * 256 + threadIdx.x) >> 6;
  int lane = threadIdx.x & 63;
  int nl = lane / 10;   // 0..5 (6 nodes per wave), lanes 60..63 idle
  int c = lane % 10;
  int n = wave * 6 + nl;
  if (nl >= 6 || n >= NN) return;
  int o0 = off[n], o1 = off[n + 1];
  float acc = 0.f;
  for (int k = o0; k < o1; k++) acc += (float)L[(size_t)k * 10 + c];
  sumin[(size_t)n * 10 + c] = acc;
}

// ---------------- fused BP step (per undirected pair) ----------------
__global__ __launch_bounds__(256) void k_bp_fused(f16* __restrict__ m,
    f16* __restrict__ L, const float* __restrict__ sumin,
    const float* __restrict__ logphi, const int* __restrict__ ei,
    const int* __restrict__ pos,
    const float* __restrict__ wp, const float* __restrict__ enp,
    const float* __restrict__ Rbuf) {
  __shared__ float Rs[104];
  if (threadIdx.x < 101) Rs[threadIdx.x] = Rbuf[threadIdx.x];
  __syncthreads();
  int p = blockIdx.x * 256 + threadIdx.x;
  if (p >= NP) return;
  const float alpha = Rs[100];
  const int s = ei[p], d = ei[NEDGE + p];
  const float w = wp[p], en = enp[p];
  const int pe = pos[p], pr = pos[p + NP];

  float Le[10], Lr[10];
  {
    const f16x2* a = (const f16x2*)(L + (size_t)pe * 10);
    const f16x2* b = (const f16x2*)(L + (size_t)pr * 10);
#pragma unroll
    for (int i = 0; i < 5; i++) {
      f16x2 u = a[i], v = b[i];
      Le[2 * i] = (float)u[0]; Le[2 * i + 1] = (float)u[1];
      Lr[2 * i] = (float)v[0]; Lr[2 * i + 1] = (float)v[1];
    }
  }
  float te[10], tr[10];
  float mxe = -1e30f, mxr = -1e30f;
  {
    const float2* sis = (const float2*)(sumin + (size_t)s * 10);
    const float2* sid = (const float2*)(sumin + (size_t)d * 10);
    const float2* lps = (const float2*)(logphi + (size_t)s * 10);
    const float2* lpd = (const float2*)(logphi + (size_t)d * 10);
#pragma unroll
    for (int i = 0; i < 5; i++) {
      float2 ss = sis[i], sd = sid[i], ps = lps[i], pd = lpd[i];
      float e0 = ps.x + alpha * (ss.x - Lr[2 * i]);
      float e1 = ps.y + alpha * (ss.y - Lr[2 * i + 1]);
      float r0 = pd.x + alpha * (sd.x - Le[2 * i]);
      float r1 = pd.y + alpha * (sd.y - Le[2 * i + 1]);
      te[2 * i] = e0; te[2 * i + 1] = e1;
      tr[2 * i] = r0; tr[2 * i + 1] = r1;
      mxe = fmaxf(mxe, fmaxf(e0, e1));
      mxr = fmaxf(mxr, fmaxf(r0, r1));
    }
  }
  float se = 0.f, sr = 0.f;
#pragma unroll
  for (int c = 0; c < NC; c++) {
    float ve = __expf(te[c] - mxe);
    float vr = __expf(tr[c] - mxr);
    te[c] = ve; tr[c] = vr;
    se += ve; sr += vr;
  }
  const float ie = 0.2f / se, ir = 0.2f / sr;
  float me[10], mr[10];
  float nse = 0.f, nsr = 0.f;
  {
    f16x2* mpe = (f16x2*)(m + (size_t)p * 10);
    f16x2* mpr = (f16x2*)(m + (size_t)(p + NP) * 10);
#pragma unroll
    for (int i = 0; i < 5; i++) {
      f16x2 u = mpe[i], v = mpr[i];
      float a0 = fmaxf(0.8f * (float)u[0] + te[2 * i] * ie, 1e-12f);
      float a1 = fmaxf(0.8f * (float)u[1] + te[2 * i + 1] * ie, 1e-12f);
      float b0 = fmaxf(0.8f * (float)v[0] + tr[2 * i] * ir, 1e-12f);
      float b1 = fmaxf(0.8f * (float)v[1] + tr[2 * i + 1] * ir, 1e-12f);
      me[2 * i] = a0; me[2 * i + 1] = a1;
      mr[2 * i] = b0; mr[2 * i + 1] = b1;
      nse += a0 + a1; nsr += b0 + b1;
    }
    const float qe = 1.f / nse, qr = 1.f / nsr;
#pragma unroll
    for (int i = 0; i < 5; i++) {
      me[2 * i] *= qe; me[2 * i + 1] *= qe;
      mr[2 * i] *= qr; mr[2 * i + 1] *= qr;
      f16x2 u, v;
      u[0] = (f16)me[2 * i]; u[1] = (f16)me[2 * i + 1];
      v[0] = (f16)mr[2 * i]; v[1] = (f16)mr[2 * i + 1];
      mpe[i] = u; mpr[i] = v;
    }
  }
  float fe[10] = {0, 0, 0, 0, 0, 0, 0, 0, 0, 0};
  float fr[10] = {0, 0, 0, 0, 0, 0, 0, 0, 0, 0};
#pragma unroll
  for (int c = 0; c < NC; c++) {
    float Ecc = __expf(w * Rs[c * NC + c]);
    fe[c] += me[c] * Ecc;
    fr[c] += mr[c] * Ecc;
#pragma unroll
    for (int dd = c + 1; dd < NC; dd++) {
      float E = __expf(w * Rs[c * NC + dd]);
      fe[dd] += me[c] * E; fe[c] += me[dd] * E;
      fr[dd] += mr[c] * E; fr[c] += mr[dd] * E;
    }
  }
  {
    f16x2* Lpe = (f16x2*)(L + (size_t)pe * 10);
    f16x2* Lpr = (f16x2*)(L + (size_t)pr * 10);
#pragma unroll
    for (int i = 0; i < 5; i++) {
      f16x2 u, v;
      u[0] = (f16)(__logf(fmaxf(fe[2 * i], 1e-12f)) * en);
      u[1] = (f16)(__logf(fmaxf(fe[2 * i + 1], 1e-12f)) * en);
      v[0] = (f16)(__logf(fmaxf(fr[2 * i], 1e-12f)) * en);
      v[1] = (f16)(__logf(fmaxf(fr[2 * i + 1], 1e-12f)) * en);
      Lpe[i] = u; Lpr[i] = v;
    }
  }
}

// ---------------- final beliefs ----------------
__global__ __launch_bounds__(256) void k_beliefs(const float* __restrict__ logphi,
    const float* __restrict__ sum_in, const float* __restrict__ Rbuf, float* __restrict__ out) {
  int n = blockIdx.x * 256 + threadIdx.x;
  if (n >= NN) return;
  float alpha = Rbuf[100];
  float t[NC];
  float mx = -1e30f;
#pragma unroll
  for (int c = 0; c < NC; c++) {
    float v = logphi[n * NC + c] + alpha * sum_in[n * NC + c];
    t[c] = v;
    mx = fmaxf(mx, v);
  }
  float ssum = 0.f;
#pragma unroll
  for (int c = 0; c < NC; c++) { float ev = __expf(t[c] - mx); t[c] = ev; ssum += ev; }
  float inv = 1.f / ssum;
#pragma unroll
  for (int c = 0; c < NC; c++) out[(size_t)n * NC + c] = t[c] * inv;
}

extern "C" void kernel_launch(void* const* d_in, const int* in_sizes, int n_in,
                              void* d_out, int out_size, void* d_ws, size_t ws_size,
                              hipStream_t stream) {
  const float* x    = (const float*)d_in[0];
  const int*   ei   = (const int*)d_in[1];
  const float* ew1  = (const float*)d_in[3];
  const float* eb1  = (const float*)d_in[4];
  const float* ew2  = (const float*)d_in[5];
  const float* eb2  = (const float*)d_in[6];
  const float* mw1  = (const float*)d_in[7];
  const float* mb1  = (const float*)d_in[8];
  const float* mw2  = (const float*)d_in[9];
  const float* mb2  = (const float*)d_in[10];
  const float* Rraw = (const float*)d_in[11];
  const float* rsl  = (const float*)d_in[12];
  const float* ml   = (const float*)d_in[13];
  float* out = (float*)d_out;

  char* ws = (char*)d_ws;
  float* Rbuf   = (float*)(ws + OFF_R);
  f16*   h      = (f16*)(ws + OFF_H);
  int*   offs   = (int*)(ws + OFF_OFFS);
  int*   cursor = (int*)(ws + OFF_CUR);
  int*   pos    = (int*)(ws + OFF_POS);
  int*   bsum   = (int*)(ws + OFF_BSUM);
  int*   bbase  = (int*)(ws + OFF_BBASE);
  float* logphi = (float*)(ws + OFF_LOGPHI);
  float* deg    = (float*)(ws + OFF_DEG);
  float* logdeg = (float*)(ws + OFF_LOGDEG);
  float* rsq    = (float*)(ws + OFF_RSQ);
  float* wpair  = (float*)(ws + OFF_WPAIR);
  float* enp    = (float*)(ws + OFF_EN);
  f16*   m      = (f16*)(ws + OFF_M);
  f16*   L      = (f16*)(ws + OFF_L);
  float* sumin  = (float*)(ws + OFF_SUMIN);
  f16*   w1t    = (f16*)(ws + OFF_W1T);
  f16*   w1te   = (f16*)(ws + OFF_W1TE);

  k_setup<<<1, 256, 0, stream>>>(Rraw, rsl, ml, mw1, ew1, Rbuf, w1t, w1te);
  hipMemsetAsync(deg, 0, NN * sizeof(float), stream);
  k_deg<<<NEDGE / 256, 256, 0, stream>>>(ei, deg);
  k_nodepost<<<(NN + 255) / 256, 256, 0, stream>>>(deg, logdeg, rsq);
  k_encoder<<<(NN + 63) / 64, 256, 0, stream>>>(x, w1te, eb1, h);
  k_logits<<<NN / 16, 256, 0, stream>>>(h, ew2, eb2, logphi);
  k_edge_mlp<<<512, 256, 0, stream>>>(h, ei, logdeg, rsq, w1t, mw1, mb1, mw2, mb2, wpair, enp);
  // CSR build (h region is dead from here on)
  k_scan1<<<SCAN_NB, 256, 0, stream>>>(deg, bsum);
  k_scan2<<<1, 256, 0, stream>>>(bsum, bbase);
  k_scan3<<<SCAN_NB, 256, 0, stream>>>(deg, bbase, offs, cursor);
  k_fill<<<NEDGE / 256, 256, 0, stream>>>(ei, cursor, pos);
  k_m0<<<NEDGE / 256, 256, 0, stream>>>(ei, logphi, m);
  k_bp_f<<<NEDGE / 256, 256, 0, stream>>>(m, wpair, enp, pos, Rbuf, L);

  const int gblocks = (NN + 23) / 24;  // 4 waves/block * 6 nodes/wave
  const int fblocks = (NP + 255) / 256;
  for (int it = 0; it < TBP; it++) {
    k_gather<<<gblocks, 256, 0, stream>>>(L, offs, sumin);
    k_bp_fused<<<fblocks, 256, 0, stream>>>(m, L, sumin, logphi, ei, pos, wpair, enp, Rbuf);
  }
  k_gather<<<gblocks, 256, 0, stream>>>(L, offs, sumin);
  k_beliefs<<<(NN + 255) / 256, 256, 0, stream>>>(logphi, sumin, Rbuf, out);
}

// Round 9
// 990.919 us; speedup vs baseline: 1.2834x; 1.0863x over previous
//
#include <hip/hip_runtime.h>
#include <hip/hip_fp16.h>

#define NN 50000
#define NP 400000
#define NEDGE 800000
#define IND 256
#define HD 128
#define NC 10
#define TBP 10
#define SCAN_NB 196  // ceil(NN/256)

typedef _Float16 f16;
typedef _Float16 f16x2 __attribute__((ext_vector_type(2)));
typedef _Float16 f16x4 __attribute__((ext_vector_type(4)));
typedef _Float16 f16x8 __attribute__((ext_vector_type(8)));
typedef unsigned short u16x8 __attribute__((ext_vector_type(8)));
typedef float f32x4 __attribute__((ext_vector_type(4)));

// ---- workspace offsets (bytes) ----
static constexpr size_t OFF_R      = 0;          // 128 f32: R[100], [100]=alpha
static constexpr size_t OFF_H      = 512;        // h fp16 [NN][128] (dead after edge_mlp)
static constexpr size_t OFF_OFFS   = 512;            // CSR off int[NN+1]   (aliases h)
static constexpr size_t OFF_CUR    = 512 + 200016;   // CSR cursor int[NN]  (aliases h)
static constexpr size_t OFF_CSR    = 512 + 400032;   // CSR edge ids int[NEDGE] (aliases h)
static constexpr size_t OFF_BSUM   = 512 + 3600032;  // int[256] block sums (aliases h)
static constexpr size_t OFF_BBASE  = 512 + 3601056;  // int[256] block bases (aliases h)
static constexpr size_t OFF_LOGPHI = 12800512;   // [NN][10] f32
static constexpr size_t OFF_DEG    = 14800512;   // [NN] f32
static constexpr size_t OFF_LOGDEG = 15000512;   // [NN] f32
static constexpr size_t OFF_RSQ    = 15200512;   // [NN] f32
static constexpr size_t OFF_WPAIR  = 15400512;   // [NP] f32
static constexpr size_t OFF_EN     = 17000512;   // [NP] f32
static constexpr size_t OFF_M      = 18600512;   // m edge-major [NEDGE][10] f16 (16MB)
static constexpr size_t OFF_L      = 50600512;   // L edge-major [NEDGE][10] f16 (16MB)
static constexpr size_t OFF_SUMIN  = 82600512;   // [NN][10] f32
static constexpr size_t OFF_W1T    = 84600512;   // edge W1^T fp16 [64][256]
static constexpr size_t OFF_W1TE   = 84633280;   // enc W1^T fp16 [128][256]

// ---------------- setup: R matrix, alpha, W1 transposes ----------------
__global__ __launch_bounds__(256) void k_setup(const float* __restrict__ Rraw,
    const float* __restrict__ rsl, const float* __restrict__ ml,
    const float* __restrict__ mw1, const float* __restrict__ ew1,
    float* __restrict__ Rbuf, f16* __restrict__ w1t, f16* __restrict__ w1te) {
  int tid = threadIdx.x;
  if (tid < 100) {
    int c = tid / 10, d = tid % 10;
    float scale = log1pf(expf(rsl[0])) + 1e-6f;
    Rbuf[tid] = scale * tanhf(0.5f * (Rraw[c * 10 + d] + Rraw[d * 10 + c]));
  } else if (tid == 100) {
    Rbuf[100] = 1.5f * (1.f / (1.f + expf(-ml[0])));  // ALPHA_MAX*sigmoid*ALPHA_SCALE
  }
  for (int idx = tid; idx < 64 * 256; idx += 256) {
    int j = idx >> 8, k = idx & 255;
    w1t[idx] = (f16)mw1[k * 64 + j];
  }
  for (int idx = tid; idx < 128 * 256; idx += 256) {
    int j = idx >> 8, k = idx & 255;
    w1te[idx] = (f16)ew1[k * HD + j];
  }
}

// ---------------- degree / node post ----------------
__global__ __launch_bounds__(256) void k_deg(const int* __restrict__ ei, float* __restrict__ deg) {
  int e = blockIdx.x * 256 + threadIdx.x;
  if (e < NEDGE) atomicAdd(&deg[ei[e]], 1.f);
}

__global__ __launch_bounds__(256) void k_nodepost(const float* __restrict__ deg,
    float* __restrict__ logdeg, float* __restrict__ rsq) {
  int i = blockIdx.x * 256 + threadIdx.x;
  if (i >= NN) return;
  float d = deg[i];
  logdeg[i] = __logf(d + 1.f);
  rsq[i] = rsqrtf(fmaxf(d, 1.f));
}

// ---------------- CSR build: 3-phase hierarchical scan ----------------
__global__ __launch_bounds__(256) void k_scan1(const float* __restrict__ deg,
    int* __restrict__ bsum) {
  int idx = blockIdx.x * 256 + threadIdx.x;
  int v = (idx < NN) ? (int)deg[idx] : 0;
#pragma unroll
  for (int o = 32; o; o >>= 1) v += __shfl_down(v, o);
  __shared__ int wsum[4];
  if ((threadIdx.x & 63) == 0) wsum[threadIdx.x >> 6] = v;
  __syncthreads();
  if (threadIdx.x == 0) bsum[blockIdx.x] = wsum[0] + wsum[1] + wsum[2] + wsum[3];
}

__global__ __launch_bounds__(256) void k_scan2(const int* __restrict__ bsum,
    int* __restrict__ bbase) {
  __shared__ int s[256];
  int t = threadIdx.x;
  int orig = (t < SCAN_NB) ? bsum[t] : 0;
  s[t] = orig;
  __syncthreads();
  for (int d = 1; d < 256; d <<= 1) {
    int v = (t >= d) ? s[t - d] : 0;
    __syncthreads();
    s[t] += v;
    __syncthreads();
  }
  bbase[t] = s[t] - orig;  // exclusive
}

__global__ __launch_bounds__(256) void k_scan3(const float* __restrict__ deg,
    const int* __restrict__ bbase, int* __restrict__ off, int* __restrict__ cursor) {
  __shared__ int s[256];
  int t = threadIdx.x;
  int idx = blockIdx.x * 256 + t;
  int d = (idx < NN) ? (int)deg[idx] : 0;
  s[t] = d;
  __syncthreads();
  for (int k = 1; k < 256; k <<= 1) {
    int v = (t >= k) ? s[t - k] : 0;
    __syncthreads();
    s[t] += v;
    __syncthreads();
  }
  int base = bbase[blockIdx.x];
  int excl = base + s[t] - d;
  if (idx < NN) {
    off[idx] = excl;
    cursor[idx] = excl;
  }
  if (idx == NN - 1) off[NN] = excl + d;
}

// fill: csr[slot] = edge id (scattered one-time write; keeps per-iter kernels coalesced)
__global__ __launch_bounds__(256) void k_fill(const int* __restrict__ ei,
    int* __restrict__ cursor, int* __restrict__ csr) {
  int e = blockIdx.x * 256 + threadIdx.x;
  if (e >= NEDGE) return;
  int d = ei[NEDGE + e];
  int slot = atomicAdd(&cursor[d], 1);
  csr[slot] = e;
}

// ---------------- encoder: h = relu(x @ W1 + b1) via MFMA f16 ----------------
__global__ __launch_bounds__(256) void k_encoder(const float* __restrict__ x,
    const f16* __restrict__ w1te, const float* __restrict__ b1, f16* __restrict__ h) {
  __shared__ f16 As[64 * 264];
  const int tid = threadIdx.x;
  const int wid = tid >> 6;
  const int lane = tid & 63;
  const int l15 = lane & 15;
  const int lhi = lane >> 4;
  const int nb = blockIdx.x * 64;
#pragma unroll
  for (int i = 0; i < 16; i++) {
    int fidx = tid + 256 * i;
    int row = fidx >> 6;
    int q = fidx & 63;
    f32x4 v = {0.f, 0.f, 0.f, 0.f};
    if (nb + row < NN) v = *(const f32x4*)(x + (size_t)(nb + row) * IND + q * 4);
    f16x4 o;
#pragma unroll
    for (int j = 0; j < 4; j++) o[j] = (f16)v[j];
    *(f16x4*)(&As[row * 264 + q * 4]) = o;
  }
  __syncthreads();
  f16x8 bfr[8][2];
#pragma unroll
  for (int ks = 0; ks < 8; ks++)
#pragma unroll
    for (int t = 0; t < 2; t++)
      bfr[ks][t] = *(const f16x8*)(w1te + (size_t)(wid * 32 + t * 16 + l15) * 256 + ks * 32 + lhi * 8);
  float b1v[2] = {b1[wid * 32 + l15], b1[wid * 32 + 16 + l15]};
  f32x4 acc[4][2] = {};
#pragma unroll
  for (int ks = 0; ks < 8; ks++) {
    f16x8 af[4];
#pragma unroll
    for (int rt = 0; rt < 4; rt++)
      af[rt] = *(const f16x8*)(&As[(rt * 16 + l15) * 264 + ks * 32 + lhi * 8]);
#pragma unroll
    for (int rt = 0; rt < 4; rt++)
#pragma unroll
      for (int t = 0; t < 2; t++)
        acc[rt][t] = __builtin_amdgcn_mfma_f32_16x16x32_f16(af[rt], bfr[ks][t], acc[rt][t], 0, 0, 0);
  }
#pragma unroll
  for (int rt = 0; rt < 4; rt++) {
#pragma unroll
    for (int t = 0; t < 2; t++) {
#pragma unroll
      for (int i = 0; i < 4; i++) {
        int row = nb + rt * 16 + lhi * 4 + i;
        if (row < NN)
          h[(size_t)row * HD + wid * 32 + t * 16 + l15] = (f16)fmaxf(acc[rt][t][i] + b1v[t], 0.f);
      }
    }
  }
}

// ---------------- logits + log_softmax(logits/1.5) ----------------
__global__ __launch_bounds__(256) void k_logits(const f16* __restrict__ h,
    const float* __restrict__ w2, const float* __restrict__ b2, float* __restrict__ logphi) {
  __shared__ float hs[16 * HD];
  __shared__ float lg[16 * NC];
  const int tid = threadIdx.x;
  const int nb = blockIdx.x * 16;
  for (int i = tid; i < 16 * HD / 8; i += 256) {
    f16x8 v = *(const f16x8*)(h + (size_t)nb * HD + i * 8);
#pragma unroll
    for (int u = 0; u < 8; u++) hs[i * 8 + u] = (float)v[u];
  }
  __syncthreads();
  if (tid < 160) {
    int n = tid / 10, c = tid % 10;
    float a = b2[c];
    for (int k = 0; k < HD; k++) a += hs[n * HD + k] * w2[k * NC + c];
    lg[n * NC + c] = a * (1.f / 1.5f);
  }
  __syncthreads();
  if (tid < 16) {
    float mx = -1e30f;
#pragma unroll
    for (int c = 0; c < NC; c++) mx = fmaxf(mx, lg[tid * NC + c]);
    float s = 0.f;
#pragma unroll
    for (int c = 0; c < NC; c++) s += __expf(lg[tid * NC + c] - mx);
    float lse = __logf(s) + mx;
#pragma unroll
    for (int c = 0; c < NC; c++)
      logphi[(size_t)(nb + tid) * NC + c] = lg[tid * NC + c] - lse;
  }
}

// ---------------- edge MLP (per undirected pair), MFMA f16 ----------------
__global__ __launch_bounds__(256) void k_edge_mlp(const f16* __restrict__ h,
    const int* __restrict__ ei, const float* __restrict__ logdeg, const float* __restrict__ rsq,
    const f16* __restrict__ w1t, const float* __restrict__ mw1, const float* __restrict__ mb1,
    const float* __restrict__ mw2, const float* __restrict__ mb2,
    float* __restrict__ w_pair, float* __restrict__ en_pair) {
  __shared__ f16 At[4][16 * 264];
  __shared__ float hidl[4][16 * 64];
  __shared__ float sfeat[4][2][16];
  const int tid = threadIdx.x;
  const int wid = tid >> 6;
  const int lane = tid & 63;
  const int l15 = lane & 15;
  const int lhi = lane >> 4;

  f16x8 bfr[8][4];
#pragma unroll
  for (int ks = 0; ks < 8; ks++)
#pragma unroll
    for (int t = 0; t < 4; t++)
      bfr[ks][t] = *(const f16x8*)(w1t + (size_t)(l15 + 16 * t) * 256 + ks * 32 + lhi * 8);

  float b1v[4], w256v[4], w257v[4];
#pragma unroll
  for (int t = 0; t < 4; t++) {
    b1v[t] = mb1[l15 + 16 * t];
    w256v[t] = mw1[256 * 64 + l15 + 16 * t];
    w257v[t] = mw1[257 * 64 + l15 + 16 * t];
  }
  float w2r[16];
#pragma unroll
  for (int jj = 0; jj < 16; jj++) w2r[jj] = mw2[lhi * 16 + jj];
  const float b2s = mb2[0];

  const int ntiles = NP / 64;  // 6250
  for (int tile = blockIdx.x; tile < ntiles; tile += gridDim.x) {
    const int pbase = tile * 64 + wid * 16;
#pragma unroll
    for (int rr = 0; rr < 4; rr++) {
      int r = rr * 4 + lhi;
      int p = pbase + r;
      int s = ei[p], d = ei[NEDGE + p];
      f16x8 hv = *(const f16x8*)(h + (size_t)s * HD + l15 * 8);
      f16x8 gv = *(const f16x8*)(h + (size_t)d * HD + l15 * 8);
      f16x8 pv = hv * gv;
      f16x8 qv = hv - gv;
      u16x8 qb = *(u16x8*)&qv;
#pragma unroll
      for (int u = 0; u < 8; u++) qb[u] &= 0x7FFF;
      qv = *(f16x8*)&qb;
      *(f16x8*)(&At[wid][r * 264 + l15 * 8]) = pv;
      *(f16x8*)(&At[wid][r * 264 + 128 + l15 * 8]) = qv;
    }
    if (lane < 16) {
      int p = pbase + lane;
      int s = ei[p], d = ei[NEDGE + p];
      float a = logdeg[s], b = logdeg[d];
      sfeat[wid][0][lane] = a + b;
      sfeat[wid][1][lane] = fabsf(a - b);
      en_pair[p] = rsq[s] * rsq[d];
    }
    __syncthreads();
    f32x4 acc[4] = {{0.f, 0.f, 0.f, 0.f}, {0.f, 0.f, 0.f, 0.f},
                    {0.f, 0.f, 0.f, 0.f}, {0.f, 0.f, 0.f, 0.f}};
#pragma unroll
    for (int ks = 0; ks < 8; ks++) {
      f16x8 af = *(const f16x8*)(&At[wid][l15 * 264 + ks * 32 + lhi * 8]);
#pragma unroll
      for (int t = 0; t < 4; t++)
        acc[t] = __builtin_amdgcn_mfma_f32_16x16x32_f16(af, bfr[ks][t], acc[t], 0, 0, 0);
    }
#pragma unroll
    for (int t = 0; t < 4; t++) {
#pragma unroll
      for (int i = 0; i < 4; i++) {
        int r = lhi * 4 + i;
        float v = acc[t][i] + sfeat[wid][0][r] * w256v[t] + sfeat[wid][1][r] * w257v[t] + b1v[t];
        hidl[wid][r * 64 + l15 + 16 * t] = fmaxf(v, 0.f);
      }
    }
    __syncthreads();
    {
      float sacc = 0.f;
#pragma unroll
      for (int jj = 0; jj < 16; jj++) sacc += hidl[wid][l15 * 64 + lhi * 16 + jj] * w2r[jj];
      sacc += __shfl_xor(sacc, 16);
      sacc += __shfl_xor(sacc, 32);
      if (lane < 16) {
        float wr = sacc + b2s;
        w_pair[pbase + lane] = 0.8f / (1.f + __expf(-wr));
      }
    }
    __syncthreads();
  }
}

// ---------------- m0 = exp(log_phi[src]) (edge-major, f16) ----------------
__global__ __launch_bounds__(256) void k_m0(const int* __restrict__ ei,
    const float* __restrict__ logphi, f16* __restrict__ m) {
  int e = blockIdx.x * 256 + threadIdx.x;
  if (e >= NEDGE) return;
  int s = ei[e];
  f16x2* mp = (f16x2*)(m + (size_t)e * 10);
  const float2* lp = (const float2*)(logphi + (size_t)s * 10);
#pragma unroll
  for (int i = 0; i < 5; i++) {
    float2 v = lp[i];
    f16x2 o;
    o[0] = (f16)__expf(v.x);
    o[1] = (f16)__expf(v.y);
    mp[i] = o;
  }
}

// ---------------- initial L (edge-major) from m0 ----------------
__global__ __launch_bounds__(256) void k_bp_f(const f16* __restrict__ m,
    const float* __restrict__ wp, const float* __restrict__ enp,
    const float* __restrict__ Rbuf, f16* __restrict__ L) {
  __shared__ float Rs[100];
  if (threadIdx.x < 100) Rs[threadIdx.x] = Rbuf[threadIdx.x];
  __syncthreads();
  int e = blockIdx.x * 256 + threadIdx.x;
  if (e >= NEDGE) return;
  int p = (e < NP) ? e : e - NP;
  float w = wp[p], en = enp[p];
  float mr[10];
  {
    const f16x2* mp = (const f16x2*)(m + (size_t)e * 10);
#pragma unroll
    for (int i = 0; i < 5; i++) { f16x2 v = mp[i]; mr[2 * i] = (float)v[0]; mr[2 * i + 1] = (float)v[1]; }
  }
  float f[10] = {0, 0, 0, 0, 0, 0, 0, 0, 0, 0};
#pragma unroll
  for (int c = 0; c < NC; c++) {
    float Ecc = __expf(w * Rs[c * NC + c]);
    f[c] += mr[c] * Ecc;
#pragma unroll
    for (int d = c + 1; d < NC; d++) {
      float Ecd = __expf(w * Rs[c * NC + d]);
      f[d] += mr[c] * Ecd;
      f[c] += mr[d] * Ecd;
    }
  }
  f16x2* Lp = (f16x2*)(L + (size_t)e * 10);
#pragma unroll
  for (int i = 0; i < 5; i++) {
    f16x2 o;
    o[0] = (f16)(__logf(fmaxf(f[2 * i], 1e-12f)) * en);
    o[1] = (f16)(__logf(fmaxf(f[2 * i + 1], 1e-12f)) * en);
    Lp[i] = o;
  }
}

// ---------------- gather: sum_in[n][c] = sum over incoming (csr slots, scattered L reads) ----------------
__global__ __launch_bounds__(256) void k_gather(const f16* __restrict__ L,
    const int* __restrict__ csr, const int* __restrict__ off, float* __restrict__ sumin) {
  int wave = (blockIdx.x * 256 + threadIdx.x) >> 6;
  int lane = threadIdx.x & 63;
  int nl = lane / 10;   // 0..5 (6 nodes per wave), lanes 60..63 idle
  int c = lane % 10;
  int n = wave * 6 + nl;
  if (nl >= 6 || n >= NN) return;
  int o0 = off[n], o1 = off[n + 1];
  float acc = 0.f;
  for (int k = o0; k < o1; k++) {
    int e = csr[k];
    acc += (float)L[(size_t)e * 10 + c];
  }
  sumin[(size_t)n * 10 + c] = acc;
}

// ---------------- fused BP step (per undirected pair, all coalesced) ----------------
__global__ __launch_bounds__(256) void k_bp_fused(f16* __restrict__ m,
    f16* __restrict__ L, const float* __restrict__ sumin,
    const float* __restrict__ logphi, const int* __restrict__ ei,
    const float* __restrict__ wp, const float* __restrict__ enp,
    const float* __restrict__ Rbuf) {
  __shared__ float Rs[104];
  if (threadIdx.x < 101) Rs[threadIdx.x] = Rbuf[threadIdx.x];
  __syncthreads();
  int p = blockIdx.x * 256 + threadIdx.x;
  if (p >= NP) return;
  const float alpha = Rs[100];
  const int s = ei[p], d = ei[NEDGE + p];
  const float w = wp[p], en = enp[p];

  float Le[10], Lr[10];
  {
    const f16x2* a = (const f16x2*)(L + (size_t)p * 10);
    const f16x2* b = (const f16x2*)(L + (size_t)(p + NP) * 10);
#pragma unroll
    for (int i = 0; i < 5; i++) {
      f16x2 u = a[i], v = b[i];
      Le[2 * i] = (float)u[0]; Le[2 * i + 1] = (float)u[1];
      Lr[2 * i] = (float)v[0]; Lr[2 * i + 1] = (float)v[1];
    }
  }
  float te[10], tr[10];
  float mxe = -1e30f, mxr = -1e30f;
  {
    const float2* sis = (const float2*)(sumin + (size_t)s * 10);
    const float2* sid = (const float2*)(sumin + (size_t)d * 10);
    const float2* lps = (const float2*)(logphi + (size_t)s * 10);
    const float2* lpd = (const float2*)(logphi + (size_t)d * 10);
#pragma unroll
    for (int i = 0; i < 5; i++) {
      float2 ss = sis[i], sd = sid[i], ps = lps[i], pd = lpd[i];
      float e0 = ps.x + alpha * (ss.x - Lr[2 * i]);
      float e1 = ps.y + alpha * (ss.y - Lr[2 * i + 1]);
      float r0 = pd.x + alpha * (sd.x - Le[2 * i]);
      float r1 = pd.y + alpha * (sd.y - Le[2 * i + 1]);
      te[2 * i] = e0; te[2 * i + 1] = e1;
      tr[2 * i] = r0; tr[2 * i + 1] = r1;
      mxe = fmaxf(mxe, fmaxf(e0, e1));
      mxr = fmaxf(mxr, fmaxf(r0, r1));
    }
  }
  float se = 0.f, sr = 0.f;
#pragma unroll
  for (int c = 0; c < NC; c++) {
    float ve = __expf(te[c] - mxe);
    float vr = __expf(tr[c] - mxr);
    te[c] = ve; tr[c] = vr;
    se += ve; sr += vr;
  }
  const float ie = 0.2f / se, ir = 0.2f / sr;
  float me[10], mr[10];
  float nse = 0.f, nsr = 0.f;
  {
    f16x2* mpe = (f16x2*)(m + (size_t)p * 10);
    f16x2* mpr = (f16x2*)(m + (size_t)(p + NP) * 10);
#pragma unroll
    for (int i = 0; i < 5; i++) {
      f16x2 u = mpe[i], v = mpr[i];
      float a0 = fmaxf(0.8f * (float)u[0] + te[2 * i] * ie, 1e-12f);
      float a1 = fmaxf(0.8f * (float)u[1] + te[2 * i + 1] * ie, 1e-12f);
      float b0 = fmaxf(0.8f * (float)v[0] + tr[2 * i] * ir, 1e-12f);
      float b1 = fmaxf(0.8f * (float)v[1] + tr[2 * i + 1] * ir, 1e-12f);
      me[2 * i] = a0; me[2 * i + 1] = a1;
      mr[2 * i] = b0; mr[2 * i + 1] = b1;
      nse += a0 + a1; nsr += b0 + b1;
    }
    const float qe = 1.f / nse, qr = 1.f / nsr;
#pragma unroll
    for (int i = 0; i < 5; i++) {
      me[2 * i] *= qe; me[2 * i + 1] *= qe;
      mr[2 * i] *= qr; mr[2 * i + 1] *= qr;
      f16x2 u, v;
      u[0] = (f16)me[2 * i]; u[1] = (f16)me[2 * i + 1];
      v[0] = (f16)mr[2 * i]; v[1] = (f16)mr[2 * i + 1];
      mpe[i] = u; mpr[i] = v;
    }
  }
  float fe[10] = {0, 0, 0, 0, 0, 0, 0, 0, 0, 0};
  float fr[10] = {0, 0, 0, 0, 0, 0, 0, 0, 0, 0};
#pragma unroll
  for (int c = 0; c < NC; c++) {
    float Ecc = __expf(w * Rs[c * NC + c]);
    fe[c] += me[c] * Ecc;
    fr[c] += mr[c] * Ecc;
#pragma unroll
    for (int dd = c + 1; dd < NC; dd++) {
      float E = __expf(w * Rs[c * NC + dd]);
      fe[dd] += me[c] * E; fe[c] += me[dd] * E;
      fr[dd] += mr[c] * E; fr[c] += mr[dd] * E;
    }
  }
  {
    f16x2* Lpe = (f16x2*)(L + (size_t)p * 10);
    f16x2* Lpr = (f16x2*)(L + (size_t)(p + NP) * 10);
#pragma unroll
    for (int i = 0; i < 5; i++) {
      f16x2 u, v;
      u[0] = (f16)(__logf(fmaxf(fe[2 * i], 1e-12f)) * en);
      u[1] = (f16)(__logf(fmaxf(fe[2 * i + 1], 1e-12f)) * en);
      v[0] = (f16)(__logf(fmaxf(fr[2 * i], 1e-12f)) * en);
      v[1] = (f16)(__logf(fmaxf(fr[2 * i + 1], 1e-12f)) * en);
      Lpe[i] = u; Lpr[i] = v;
    }
  }
}

// ---------------- final beliefs ----------------
__global__ __launch_bounds__(256) void k_beliefs(const float* __restrict__ logphi,
    const float* __restrict__ sum_in, const float* __restrict__ Rbuf, float* __restrict__ out) {
  int n = blockIdx.x * 256 + threadIdx.x;
  if (n >= NN) return;
  float alpha = Rbuf[100];
  float t[NC];
  float mx = -1e30f;
#pragma unroll
  for (int c = 0; c < NC; c++) {
    float v = logphi[n * NC + c] + alpha * sum_in[n * NC + c];
    t[c] = v;
    mx = fmaxf(mx, v);
  }
  float ssum = 0.f;
#pragma unroll
  for (int c = 0; c < NC; c++) { float ev = __expf(t[c] - mx); t[c] = ev; ssum += ev; }
  float inv = 1.f / ssum;
#pragma unroll
  for (int c = 0; c < NC; c++) out[(size_t)n * NC + c] = t[c] * inv;
}

extern "C" void kernel_launch(void* const* d_in, const int* in_sizes, int n_in,
                              void* d_out, int out_size, void* d_ws, size_t ws_size,
                              hipStream_t stream) {
  const float* x    = (const float*)d_in[0];
  const int*   ei   = (const int*)d_in[1];
  const float* ew1  = (const float*)d_in[3];
  const float* eb1  = (const float*)d_in[4];
  const float* ew2  = (const float*)d_in[5];
  const float* eb2  = (const float*)d_in[6];
  const float* mw1  = (const float*)d_in[7];
  const float* mb1  = (const float*)d_in[8];
  const float* mw2  = (const float*)d_in[9];
  const float* mb2  = (const float*)d_in[10];
  const float* Rraw = (const float*)d_in[11];
  const float* rsl  = (const float*)d_in[12];
  const float* ml   = (const float*)d_in[13];
  float* out = (float*)d_out;

  char* ws = (char*)d_ws;
  float* Rbuf   = (float*)(ws + OFF_R);
  f16*   h      = (f16*)(ws + OFF_H);
  int*   offs   = (int*)(ws + OFF_OFFS);
  int*   cursor = (int*)(ws + OFF_CUR);
  int*   csr    = (int*)(ws + OFF_CSR);
  int*   bsum   = (int*)(ws + OFF_BSUM);
  int*   bbase  = (int*)(ws + OFF_BBASE);
  float* logphi = (float*)(ws + OFF_LOGPHI);
  float* deg    = (float*)(ws + OFF_DEG);
  float* logdeg = (float*)(ws + OFF_LOGDEG);
  float* rsq    = (float*)(ws + OFF_RSQ);
  float* wpair  = (float*)(ws + OFF_WPAIR);
  float* enp    = (float*)(ws + OFF_EN);
  f16*   m      = (f16*)(ws + OFF_M);
  f16*   L      = (f16*)(ws + OFF_L);
  float* sumin  = (float*)(ws + OFF_SUMIN);
  f16*   w1t    = (f16*)(ws + OFF_W1T);
  f16*   w1te   = (f16*)(ws + OFF_W1TE);

  k_setup<<<1, 256, 0, stream>>>(Rraw, rsl, ml, mw1, ew1, Rbuf, w1t, w1te);
  hipMemsetAsync(deg, 0, NN * sizeof(float), stream);
  k_deg<<<NEDGE / 256, 256, 0, stream>>>(ei, deg);
  k_nodepost<<<(NN + 255) / 256, 256, 0, stream>>>(deg, logdeg, rsq);
  k_encoder<<<(NN + 63) / 64, 256, 0, stream>>>(x, w1te, eb1, h);
  k_logits<<<NN / 16, 256, 0, stream>>>(h, ew2, eb2, logphi);
  k_edge_mlp<<<512, 256, 0, stream>>>(h, ei, logdeg, rsq, w1t, mw1, mb1, mw2, mb2, wpair, enp);
  // CSR build (h region is dead from here on)
  k_scan1<<<SCAN_NB, 256, 0, stream>>>(deg, bsum);
  k_scan2<<<1, 256, 0, stream>>>(bsum, bbase);
  k_scan3<<<SCAN_NB, 256, 0, stream>>>(deg, bbase, offs, cursor);
  k_fill<<<NEDGE / 256, 256, 0, stream>>>(ei, cursor, csr);
  k_m0<<<NEDGE / 256, 256, 0, stream>>>(ei, logphi, m);
  k_bp_f<<<NEDGE / 256, 256, 0, stream>>>(m, wpair, enp, Rbuf, L);

  const int gblocks = (NN + 23) / 24;  // 4 waves/block * 6 nodes/wave
  const int fblocks = (NP + 255) / 256;
  for (int it = 0; it < TBP; it++) {
    k_gather<<<gblocks, 256, 0, stream>>>(L, csr, offs, sumin);
    k_bp_fused<<<fblocks, 256, 0, stream>>>(m, L, sumin, logphi, ei, wpair, enp, Rbuf);
  }
  k_gather<<<gblocks, 256, 0, stream>>>(L, csr, offs, sumin);
  k_beliefs<<<(NN + 255) / 256, 256, 0, stream>>>(logphi, sumin, Rbuf, out);
}

// Round 12
// 988.849 us; speedup vs baseline: 1.2861x; 1.0021x over previous
//
#include <hip/hip_runtime.h>
#include <hip/hip_fp16.h>
#include <hip/hip_cooperative_groups.h>

namespace cg = cooperative_groups;

#define NN 50000
#define NP 400000
#define NEDGE 800000
#define IND 256
#define HD 128
#define NC 10
#define TBP 10
#define SCAN_NB 196  // ceil(NN/256)
#define NCU 256

typedef _Float16 f16;
typedef _Float16 f16x2 __attribute__((ext_vector_type(2)));
typedef _Float16 f16x4 __attribute__((ext_vector_type(4)));
typedef _Float16 f16x8 __attribute__((ext_vector_type(8)));
typedef unsigned short u16x8 __attribute__((ext_vector_type(8)));
typedef float f32x4 __attribute__((ext_vector_type(4)));

// ---- workspace offsets (bytes) ----
static constexpr size_t OFF_R      = 0;
static constexpr size_t OFF_H      = 512;            // h fp16 [NN][128] (dead after edge_mlp)
static constexpr size_t OFF_OFFS   = 512;            // CSR off int[NN+1]   (aliases h)
static constexpr size_t OFF_CUR    = 512 + 200016;   // CSR cursor int[NN]  (aliases h)
static constexpr size_t OFF_CSR    = 512 + 400032;   // CSR edge ids int[NEDGE] (aliases h)
static constexpr size_t OFF_BSUM   = 512 + 3600032;  // int[256] block sums (aliases h)
static constexpr size_t OFF_BBASE  = 512 + 3601056;  // int[256] block bases (aliases h)
static constexpr size_t OFF_LOGPHI = 12800512;   // [NN][10] f32
static constexpr size_t OFF_DEG    = 14800512;   // [NN] f32
static constexpr size_t OFF_LOGDEG = 15000512;   // [NN] f32
static constexpr size_t OFF_RSQ    = 15200512;   // [NN] f32
static constexpr size_t OFF_WPAIR  = 15400512;   // [NP] f32
static constexpr size_t OFF_EN     = 17000512;   // [NP] f32
static constexpr size_t OFF_M      = 18600512;   // m edge-major [NEDGE][10] f16 (16MB, fallback path)
static constexpr size_t OFF_L      = 50600512;   // L edge-major [NEDGE][10] f16 (16MB)
static constexpr size_t OFF_SUMIN  = 82600512;   // [NN][10] f32
static constexpr size_t OFF_W1T    = 84600512;   // edge W1^T fp16 [64][256]
static constexpr size_t OFF_W1TE   = 84633280;   // enc W1^T fp16 [128][256]

// ---------------- setup: R matrix, alpha, W1 transposes ----------------
__global__ __launch_bounds__(256) void k_setup(const float* __restrict__ Rraw,
    const float* __restrict__ rsl, const float* __restrict__ ml,
    const float* __restrict__ mw1, const float* __restrict__ ew1,
    float* __restrict__ Rbuf, f16* __restrict__ w1t, f16* __restrict__ w1te) {
  int tid = threadIdx.x;
  if (tid < 100) {
    int c = tid / 10, d = tid % 10;
    float scale = log1pf(expf(rsl[0])) + 1e-6f;
    Rbuf[tid] = scale * tanhf(0.5f * (Rraw[c * 10 + d] + Rraw[d * 10 + c]));
  } else if (tid == 100) {
    Rbuf[100] = 1.5f * (1.f / (1.f + expf(-ml[0])));
  }
  for (int idx = tid; idx < 64 * 256; idx += 256) {
    int j = idx >> 8, k = idx & 255;
    w1t[idx] = (f16)mw1[k * 64 + j];
  }
  for (int idx = tid; idx < 128 * 256; idx += 256) {
    int j = idx >> 8, k = idx & 255;
    w1te[idx] = (f16)ew1[k * HD + j];
  }
}

// ---------------- degree / node post ----------------
__global__ __launch_bounds__(256) void k_deg(const int* __restrict__ ei, float* __restrict__ deg) {
  int e = blockIdx.x * 256 + threadIdx.x;
  if (e < NEDGE) atomicAdd(&deg[ei[e]], 1.f);
}

__global__ __launch_bounds__(256) void k_nodepost(const float* __restrict__ deg,
    float* __restrict__ logdeg, float* __restrict__ rsq) {
  int i = blockIdx.x * 256 + threadIdx.x;
  if (i >= NN) return;
  float d = deg[i];
  logdeg[i] = __logf(d + 1.f);
  rsq[i] = rsqrtf(fmaxf(d, 1.f));
}

// ---------------- CSR build: 3-phase hierarchical scan ----------------
__global__ __launch_bounds__(256) void k_scan1(const float* __restrict__ deg,
    int* __restrict__ bsum) {
  int idx = blockIdx.x * 256 + threadIdx.x;
  int v = (idx < NN) ? (int)deg[idx] : 0;
#pragma unroll
  for (int o = 32; o; o >>= 1) v += __shfl_down(v, o);
  __shared__ int wsum[4];
  if ((threadIdx.x & 63) == 0) wsum[threadIdx.x >> 6] = v;
  __syncthreads();
  if (threadIdx.x == 0) bsum[blockIdx.x] = wsum[0] + wsum[1] + wsum[2] + wsum[3];
}

__global__ __launch_bounds__(256) void k_scan2(const int* __restrict__ bsum,
    int* __restrict__ bbase) {
  __shared__ int s[256];
  int t = threadIdx.x;
  int orig = (t < SCAN_NB) ? bsum[t] : 0;
  s[t] = orig;
  __syncthreads();
  for (int d = 1; d < 256; d <<= 1) {
    int v = (t >= d) ? s[t - d] : 0;
    __syncthreads();
    s[t] += v;
    __syncthreads();
  }
  bbase[t] = s[t] - orig;  // exclusive
}

__global__ __launch_bounds__(256) void k_scan3(const float* __restrict__ deg,
    const int* __restrict__ bbase, int* __restrict__ off, int* __restrict__ cursor) {
  __shared__ int s[256];
  int t = threadIdx.x;
  int idx = blockIdx.x * 256 + t;
  int d = (idx < NN) ? (int)deg[idx] : 0;
  s[t] = d;
  __syncthreads();
  for (int k = 1; k < 256; k <<= 1) {
    int v = (t >= k) ? s[t - k] : 0;
    __syncthreads();
    s[t] += v;
    __syncthreads();
  }
  int base = bbase[blockIdx.x];
  int excl = base + s[t] - d;
  if (idx < NN) {
    off[idx] = excl;
    cursor[idx] = excl;
  }
  if (idx == NN - 1) off[NN] = excl + d;
}

__global__ __launch_bounds__(256) void k_fill(const int* __restrict__ ei,
    int* __restrict__ cursor, int* __restrict__ csr) {
  int e = blockIdx.x * 256 + threadIdx.x;
  if (e >= NEDGE) return;
  int d = ei[NEDGE + e];
  int slot = atomicAdd(&cursor[d], 1);
  csr[slot] = e;
}

// ---------------- encoder: h = relu(x @ W1 + b1) via MFMA f16 ----------------
__global__ __launch_bounds__(256) void k_encoder(const float* __restrict__ x,
    const f16* __restrict__ w1te, const float* __restrict__ b1, f16* __restrict__ h) {
  __shared__ f16 As[64 * 264];
  const int tid = threadIdx.x;
  const int wid = tid >> 6;
  const int lane = tid & 63;
  const int l15 = lane & 15;
  const int lhi = lane >> 4;
  const int nb = blockIdx.x * 64;
#pragma unroll
  for (int i = 0; i < 16; i++) {
    int fidx = tid + 256 * i;
    int row = fidx >> 6;
    int q = fidx & 63;
    f32x4 v = {0.f, 0.f, 0.f, 0.f};
    if (nb + row < NN) v = *(const f32x4*)(x + (size_t)(nb + row) * IND + q * 4);
    f16x4 o;
#pragma unroll
    for (int j = 0; j < 4; j++) o[j] = (f16)v[j];
    *(f16x4*)(&As[row * 264 + q * 4]) = o;
  }
  __syncthreads();
  f16x8 bfr[8][2];
#pragma unroll
  for (int ks = 0; ks < 8; ks++)
#pragma unroll
    for (int t = 0; t < 2; t++)
      bfr[ks][t] = *(const f16x8*)(w1te + (size_t)(wid * 32 + t * 16 + l15) * 256 + ks * 32 + lhi * 8);
  float b1v[2] = {b1[wid * 32 + l15], b1[wid * 32 + 16 + l15]};
  f32x4 acc[4][2] = {};
#pragma unroll
  for (int ks = 0; ks < 8; ks++) {
    f16x8 af[4];
#pragma unroll
    for (int rt = 0; rt < 4; rt++)
      af[rt] = *(const f16x8*)(&As[(rt * 16 + l15) * 264 + ks * 32 + lhi * 8]);
#pragma unroll
    for (int rt = 0; rt < 4; rt++)
#pragma unroll
      for (int t = 0; t < 2; t++)
        acc[rt][t] = __builtin_amdgcn_mfma_f32_16x16x32_f16(af[rt], bfr[ks][t], acc[rt][t], 0, 0, 0);
  }
#pragma unroll
  for (int rt = 0; rt < 4; rt++) {
#pragma unroll
    for (int t = 0; t < 2; t++) {
#pragma unroll
      for (int i = 0; i < 4; i++) {
        int row = nb + rt * 16 + lhi * 4 + i;
        if (row < NN)
          h[(size_t)row * HD + wid * 32 + t * 16 + l15] = (f16)fmaxf(acc[rt][t][i] + b1v[t], 0.f);
      }
    }
  }
}

// ---------------- logits + log_softmax(logits/1.5) ----------------
__global__ __launch_bounds__(256) void k_logits(const f16* __restrict__ h,
    const float* __restrict__ w2, const float* __restrict__ b2, float* __restrict__ logphi) {
  __shared__ float hs[16 * HD];
  __shared__ float lg[16 * NC];
  const int tid = threadIdx.x;
  const int nb = blockIdx.x * 16;
  for (int i = tid; i < 16 * HD / 8; i += 256) {
    f16x8 v = *(const f16x8*)(h + (size_t)nb * HD + i * 8);
#pragma unroll
    for (int u = 0; u < 8; u++) hs[i * 8 + u] = (float)v[u];
  }
  __syncthreads();
  if (tid < 160) {
    int n = tid / 10, c = tid % 10;
    float a = b2[c];
    for (int k = 0; k < HD; k++) a += hs[n * HD + k] * w2[k * NC + c];
    lg[n * NC + c] = a * (1.f / 1.5f);
  }
  __syncthreads();
  if (tid < 16) {
    float mx = -1e30f;
#pragma unroll
    for (int c = 0; c < NC; c++) mx = fmaxf(mx, lg[tid * NC + c]);
    float s = 0.f;
#pragma unroll
    for (int c = 0; c < NC; c++) s += __expf(lg[tid * NC + c] - mx);
    float lse = __logf(s) + mx;
#pragma unroll
    for (int c = 0; c < NC; c++)
      logphi[(size_t)(nb + tid) * NC + c] = lg[tid * NC + c] - lse;
  }
}

// ---------------- edge MLP (per undirected pair), MFMA f16 ----------------
__global__ __launch_bounds__(256) void k_edge_mlp(const f16* __restrict__ h,
    const int* __restrict__ ei, const float* __restrict__ logdeg, const float* __restrict__ rsq,
    const f16* __restrict__ w1t, const float* __restrict__ mw1, const float* __restrict__ mb1,
    const float* __restrict__ mw2, const float* __restrict__ mb2,
    float* __restrict__ w_pair, float* __restrict__ en_pair) {
  __shared__ f16 At[4][16 * 264];
  __shared__ float hidl[4][16 * 64];
  __shared__ float sfeat[4][2][16];
  const int tid = threadIdx.x;
  const int wid = tid >> 6;
  const int lane = tid & 63;
  const int l15 = lane & 15;
  const int lhi = lane >> 4;

  f16x8 bfr[8][4];
#pragma unroll
  for (int ks = 0; ks < 8; ks++)
#pragma unroll
    for (int t = 0; t < 4; t++)
      bfr[ks][t] = *(const f16x8*)(w1t + (size_t)(l15 + 16 * t) * 256 + ks * 32 + lhi * 8);

  float b1v[4], w256v[4], w257v[4];
#pragma unroll
  for (int t = 0; t < 4; t++) {
    b1v[t] = mb1[l15 + 16 * t];
    w256v[t] = mw1[256 * 64 + l15 + 16 * t];
    w257v[t] = mw1[257 * 64 + l15 + 16 * t];
  }
  float w2r[16];
#pragma unroll
  for (int jj = 0; jj < 16; jj++) w2r[jj] = mw2[lhi * 16 + jj];
  const float b2s = mb2[0];

  const int ntiles = NP / 64;
  for (int tile = blockIdx.x; tile < ntiles; tile += gridDim.x) {
    const int pbase = tile * 64 + wid * 16;
#pragma unroll
    for (int rr = 0; rr < 4; rr++) {
      int r = rr * 4 + lhi;
      int p = pbase + r;
      int s = ei[p], d = ei[NEDGE + p];
      f16x8 hv = *(const f16x8*)(h + (size_t)s * HD + l15 * 8);
      f16x8 gv = *(const f16x8*)(h + (size_t)d * HD + l15 * 8);
      f16x8 pv = hv * gv;
      f16x8 qv = hv - gv;
      u16x8 qb = *(u16x8*)&qv;
#pragma unroll
      for (int u = 0; u < 8; u++) qb[u] &= 0x7FFF;
      qv = *(f16x8*)&qb;
      *(f16x8*)(&At[wid][r * 264 + l15 * 8]) = pv;
      *(f16x8*)(&At[wid][r * 264 + 128 + l15 * 8]) = qv;
    }
    if (lane < 16) {
      int p = pbase + lane;
      int s = ei[p], d = ei[NEDGE + p];
      float a = logdeg[s], b = logdeg[d];
      sfeat[wid][0][lane] = a + b;
      sfeat[wid][1][lane] = fabsf(a - b);
      en_pair[p] = rsq[s] * rsq[d];
    }
    __syncthreads();
    f32x4 acc[4] = {{0.f, 0.f, 0.f, 0.f}, {0.f, 0.f, 0.f, 0.f},
                    {0.f, 0.f, 0.f, 0.f}, {0.f, 0.f, 0.f, 0.f}};
#pragma unroll
    for (int ks = 0; ks < 8; ks++) {
      f16x8 af = *(const f16x8*)(&At[wid][l15 * 264 + ks * 32 + lhi * 8]);
#pragma unroll
      for (int t = 0; t < 4; t++)
        acc[t] = __builtin_amdgcn_mfma_f32_16x16x32_f16(af, bfr[ks][t], acc[t], 0, 0, 0);
    }
#pragma unroll
    for (int t = 0; t < 4; t++) {
#pragma unroll
      for (int i = 0; i < 4; i++) {
        int r = lhi * 4 + i;
        float v = acc[t][i] + sfeat[wid][0][r] * w256v[t] + sfeat[wid][1][r] * w257v[t] + b1v[t];
        hidl[wid][r * 64 + l15 + 16 * t] = fmaxf(v, 0.f);
      }
    }
    __syncthreads();
    {
      float sacc = 0.f;
#pragma unroll
      for (int jj = 0; jj < 16; jj++) sacc += hidl[wid][l15 * 64 + lhi * 16 + jj] * w2r[jj];
      sacc += __shfl_xor(sacc, 16);
      sacc += __shfl_xor(sacc, 32);
      if (lane < 16) {
        float wr = sacc + b2s;
        w_pair[pbase + lane] = 0.8f / (1.f + __expf(-wr));
      }
    }
    __syncthreads();
  }
}

// ================= fallback (round-9 proven) BP kernels =================
__global__ __launch_bounds__(256) void k_m0(const int* __restrict__ ei,
    const float* __restrict__ logphi, f16* __restrict__ m) {
  int e = blockIdx.x * 256 + threadIdx.x;
  if (e >= NEDGE) return;
  int s = ei[e];
  f16x2* mp = (f16x2*)(m + (size_t)e * 10);
  const float2* lp = (const float2*)(logphi + (size_t)s * 10);
#pragma unroll
  for (int i = 0; i < 5; i++) {
    float2 v = lp[i];
    f16x2 o;
    o[0] = (f16)__expf(v.x);
    o[1] = (f16)__expf(v.y);
    mp[i] = o;
  }
}

__global__ __launch_bounds__(256) void k_bp_f(const f16* __restrict__ m,
    const float* __restrict__ wp, const float* __restrict__ enp,
    const float* __restrict__ Rbuf, f16* __restrict__ L) {
  __shared__ float Rs[100];
  if (threadIdx.x < 100) Rs[threadIdx.x] = Rbuf[threadIdx.x];
  __syncthreads();
  int e = blockIdx.x * 256 + threadIdx.x;
  if (e >= NEDGE) return;
  int p = (e < NP) ? e : e - NP;
  float w = wp[p], en = enp[p];
  float mr[10];
  {
    const f16x2* mp = (const f16x2*)(m + (size_t)e * 10);
#pragma unroll
    for (int i = 0; i < 5; i++) { f16x2 v = mp[i]; mr[2 * i] = (float)v[0]; mr[2 * i + 1] = (float)v[1]; }
  }
  float f[10] = {0, 0, 0, 0, 0, 0, 0, 0, 0, 0};
#pragma unroll
  for (int c = 0; c < NC; c++) {
    float Ecc = __expf(w * Rs[c * NC + c]);
    f[c] += mr[c] * Ecc;
#pragma unroll
    for (int d = c + 1; d < NC; d++) {
      float Ecd = __expf(w * Rs[c * NC + d]);
      f[d] += mr[c] * Ecd;
      f[c] += mr[d] * Ecd;
    }
  }
  f16x2* Lp = (f16x2*)(L + (size_t)e * 10);
#pragma unroll
  for (int i = 0; i < 5; i++) {
    f16x2 o;
    o[0] = (f16)(__logf(fmaxf(f[2 * i], 1e-12f)) * en);
    o[1] = (f16)(__logf(fmaxf(f[2 * i + 1], 1e-12f)) * en);
    Lp[i] = o;
  }
}

__global__ __launch_bounds__(256) void k_gather(const f16* __restrict__ L,
    const int* __restrict__ csr, const int* __restrict__ off, float* __restrict__ sumin) {
  int wave = (blockIdx.x * 256 + threadIdx.x) >> 6;
  int lane = threadIdx.x & 63;
  int nl = lane / 10;
  int c = lane % 10;
  int n = wave * 6 + nl;
  if (nl >= 6 || n >= NN) return;
  int o0 = off[n], o1 = off[n + 1];
  float acc = 0.f;
  for (int k = o0; k < o1; k++) {
    int e = csr[k];
    acc += (float)L[(size_t)e * 10 + c];
  }
  sumin[(size_t)n * 10 + c] = acc;
}

__global__ __launch_bounds__(256) void k_bp_fused(f16* __restrict__ m,
    f16* __restrict__ L, const float* __restrict__ sumin,
    const float* __restrict__ logphi, const int* __restrict__ ei,
    const float* __restrict__ wp, const float* __restrict__ enp,
    const float* __restrict__ Rbuf) {
  __shared__ float Rs[104];
  if (threadIdx.x < 101) Rs[threadIdx.x] = Rbuf[threadIdx.x];
  __syncthreads();
  int p = blockIdx.x * 256 + threadIdx.x;
  if (p >= NP) return;
  const float alpha = Rs[100];
  const int s = ei[p], d = ei[NEDGE + p];
  const float w = wp[p], en = enp[p];

  float Le[10], Lr[10];
  {
    const f16x2* a = (const f16x2*)(L + (size_t)p * 10);
    const f16x2* b = (const f16x2*)(L + (size_t)(p + NP) * 10);
#pragma unroll
    for (int i = 0; i < 5; i++) {
      f16x2 u = a[i], v = b[i];
      Le[2 * i] = (float)u[0]; Le[2 * i + 1] = (float)u[1];
      Lr[2 * i] = (float)v[0]; Lr[2 * i + 1] = (float)v[1];
    }
  }
  float te[10], tr[10];
  float mxe = -1e30f, mxr = -1e30f;
  {
    const float2* sis = (const float2*)(sumin + (size_t)s * 10);
    const float2* sid = (const float2*)(sumin + (size_t)d * 10);
    const float2* lps = (const float2*)(logphi + (size_t)s * 10);
    const float2* lpd = (const float2*)(logphi + (size_t)d * 10);
#pragma unroll
    for (int i = 0; i < 5; i++) {
      float2 ss = sis[i], sd = sid[i], ps = lps[i], pd = lpd[i];
      float e0 = ps.x + alpha * (ss.x - Lr[2 * i]);
      float e1 = ps.y + alpha * (ss.y - Lr[2 * i + 1]);
      float r0 = pd.x + alpha * (sd.x - Le[2 * i]);
      float r1 = pd.y + alpha * (sd.y - Le[2 * i + 1]);
      te[2 * i] = e0; te[2 * i + 1] = e1;
      tr[2 * i] = r0; tr[2 * i + 1] = r1;
      mxe = fmaxf(mxe, fmaxf(e0, e1));
      mxr = fmaxf(mxr, fmaxf(r0, r1));
    }
  }
  float se = 0.f, sr = 0.f;
#pragma unroll
  for (int c = 0; c < NC; c++) {
    float ve = __expf(te[c] - mxe);
    float vr = __expf(tr[c] - mxr);
    te[c] = ve; tr[c] = vr;
    se += ve; sr += vr;
  }
  const float ie = 0.2f / se, ir = 0.2f / sr;
  float me[10], mr[10];
  float nse = 0.f, nsr = 0.f;
  {
    f16x2* mpe = (f16x2*)(m + (size_t)p * 10);
    f16x2* mpr = (f16x2*)(m + (size_t)(p + NP) * 10);
#pragma unroll
    for (int i = 0; i < 5; i++) {
      f16x2 u = mpe[i], v = mpr[i];
      float a0 = fmaxf(0.8f * (float)u[0] + te[2 * i] * ie, 1e-12f);
      float a1 = fmaxf(0.8f * (float)u[1] + te[2 * i + 1] * ie, 1e-12f);
      float b0 = fmaxf(0.8f * (float)v[0] + tr[2 * i] * ir, 1e-12f);
      float b1 = fmaxf(0.8f * (float)v[1] + tr[2 * i + 1] * ir, 1e-12f);
      me[2 * i] = a0; me[2 * i + 1] = a1;
      mr[2 * i] = b0; mr[2 * i + 1] = b1;
      nse += a0 + a1; nsr += b0 + b1;
    }
    const float qe = 1.f / nse, qr = 1.f / nsr;
#pragma unroll
    for (int i = 0; i < 5; i++) {
      me[2 * i] *= qe; me[2 * i + 1] *= qe;
      mr[2 * i] *= qr; mr[2 * i + 1] *= qr;
      f16x2 u, v;
      u[0] = (f16)me[2 * i]; u[1] = (f16)me[2 * i + 1];
      v[0] = (f16)mr[2 * i]; v[1] = (f16)mr[2 * i + 1];
      mpe[i] = u; mpr[i] = v;
    }
  }
  float fe[10] = {0, 0, 0, 0, 0, 0, 0, 0, 0, 0};
  float fr[10] = {0, 0, 0, 0, 0, 0, 0, 0, 0, 0};
#pragma unroll
  for (int c = 0; c < NC; c++) {
    float Ecc = __expf(w * Rs[c * NC + c]);
    fe[c] += me[c] * Ecc;
    fr[c] += mr[c] * Ecc;
#pragma unroll
    for (int dd = c + 1; dd < NC; dd++) {
      float E = __expf(w * Rs[c * NC + dd]);
      fe[dd] += me[c] * E; fe[c] += me[dd] * E;
      fr[dd] += mr[c] * E; fr[c] += mr[dd] * E;
    }
  }
  {
    f16x2* Lpe = (f16x2*)(L + (size_t)p * 10);
    f16x2* Lpr = (f16x2*)(L + (size_t)(p + NP) * 10);
#pragma unroll
    for (int i = 0; i < 5; i++) {
      f16x2 u, v;
      u[0] = (f16)(__logf(fmaxf(fe[2 * i], 1e-12f)) * en);
      u[1] = (f16)(__logf(fmaxf(fe[2 * i + 1], 1e-12f)) * en);
      v[0] = (f16)(__logf(fmaxf(fr[2 * i], 1e-12f)) * en);
      v[1] = (f16)(__logf(fmaxf(fr[2 * i + 1], 1e-12f)) * en);
      Lpe[i] = u; Lpr[i] = v;
    }
  }
}

// ================= persistent cooperative BP loop (dynamic grid) =================
// Dataflow bit-identical to k_m0/k_bp_f/k_gather/k_bp_fused chain.
__global__ __launch_bounds__(256, 2) void k_coop(
    const int* __restrict__ ei, const float* __restrict__ wp, const float* __restrict__ enp,
    const float* __restrict__ logphi, const float* __restrict__ Rbuf,
    f16* __restrict__ L, float* __restrict__ sumin,
    const int* __restrict__ csr, const int* __restrict__ offs) {
  cg::grid_group grid = cg::this_grid();
  __shared__ float Rs[104];
  if (threadIdx.x < 101) Rs[threadIdx.x] = Rbuf[threadIdx.x];
  __syncthreads();
  const float alpha = Rs[100];
  const int T = (int)gridDim.x * 256;   // total threads (runtime)
  const int tid = blockIdx.x * 256 + threadIdx.x;
  const int lane = threadIdx.x & 63;
  const int gwave = tid >> 6;
  const int waves = T >> 6;
  const int npw = (NN + waves - 1) / waves;
  const int nl = lane / 10;
  const int ch = lane % 10;

  int sA[4], dA[4];
  float wA[4], enA[4];
  f16x2 mP[4][10];  // [slot][0..4]=me, [5..9]=mr
  f16x2 lP[4][10];  // [slot][0..4]=Le, [5..9]=Lr

  // ---- init: m0 = f16(exp(logphi[src])); L0 = log(K m0_f16)*en ----
#pragma unroll
  for (int sl = 0; sl < 4; sl++) {
    int p = tid + sl * T;
    if (p >= NP) { sA[sl] = -1; continue; }
    int sn = ei[p], dn = ei[NEDGE + p];
    float w = wp[p], en = enp[p];
    sA[sl] = sn; dA[sl] = dn; wA[sl] = w; enA[sl] = en;
    float me[10], mr[10];
    {
      const float2* lps = (const float2*)(logphi + (size_t)sn * 10);
      const float2* lpd = (const float2*)(logphi + (size_t)dn * 10);
#pragma unroll
      for (int i = 0; i < 5; i++) {
        float2 a = lps[i], b = lpd[i];
        f16x2 u, v;
        u[0] = (f16)__expf(a.x); u[1] = (f16)__expf(a.y);
        v[0] = (f16)__expf(b.x); v[1] = (f16)__expf(b.y);
        mP[sl][i] = u; mP[sl][5 + i] = v;
        me[2 * i] = (float)u[0]; me[2 * i + 1] = (float)u[1];
        mr[2 * i] = (float)v[0]; mr[2 * i + 1] = (float)v[1];
      }
    }
    float fe[10] = {0, 0, 0, 0, 0, 0, 0, 0, 0, 0};
    float fr[10] = {0, 0, 0, 0, 0, 0, 0, 0, 0, 0};
#pragma unroll
    for (int c = 0; c < NC; c++) {
      float Ecc = __expf(w * Rs[c * NC + c]);
      fe[c] += me[c] * Ecc;
      fr[c] += mr[c] * Ecc;
#pragma unroll
      for (int dd = c + 1; dd < NC; dd++) {
        float E = __expf(w * Rs[c * NC + dd]);
        fe[dd] += me[c] * E; fe[c] += me[dd] * E;
        fr[dd] += mr[c] * E; fr[c] += mr[dd] * E;
      }
    }
    f16x2* Lpe = (f16x2*)(L + (size_t)p * 10);
    f16x2* Lpr = (f16x2*)(L + (size_t)(p + NP) * 10);
#pragma unroll
    for (int i = 0; i < 5; i++) {
      f16x2 u, v;
      u[0] = (f16)(__logf(fmaxf(fe[2 * i], 1e-12f)) * en);
      u[1] = (f16)(__logf(fmaxf(fe[2 * i + 1], 1e-12f)) * en);
      v[0] = (f16)(__logf(fmaxf(fr[2 * i], 1e-12f)) * en);
      v[1] = (f16)(__logf(fmaxf(fr[2 * i + 1], 1e-12f)) * en);
      lP[sl][i] = u; lP[sl][5 + i] = v;
      Lpe[i] = u; Lpr[i] = v;
    }
  }

  for (int it = 0; it <= TBP; it++) {
    grid.sync();  // L writes visible
    // ---- gather: sumin[n][c] over incoming edges (CSR slot order) ----
    if (nl < 6) {
      int nb = gwave * npw;
      for (int n0 = 0; n0 < npw; n0 += 6) {
        int n = nb + n0 + nl;
        if (n < nb + npw && n < NN) {
          int o0 = offs[n], o1 = offs[n + 1];
          float acc = 0.f;
          for (int k = o0; k < o1; k++)
            acc += (float)L[(size_t)csr[k] * 10 + ch];
          sumin[(size_t)n * 10 + ch] = acc;
        }
      }
    }
    if (it == TBP) break;
    grid.sync();  // sumin visible
    // ---- fused: update m (regs), write new L ----
#pragma unroll
    for (int sl = 0; sl < 4; sl++) {
      if (sA[sl] < 0) continue;
      const int p = tid + sl * T;
      const int sn = sA[sl], dn = dA[sl];
      const float w = wA[sl], en = enA[sl];
      float te[10], tr[10];
      float mxe = -1e30f, mxr = -1e30f;
      {
        const float2* sis = (const float2*)(sumin + (size_t)sn * 10);
        const float2* sid = (const float2*)(sumin + (size_t)dn * 10);
        const float2* lps = (const float2*)(logphi + (size_t)sn * 10);
        const float2* lpd = (const float2*)(logphi + (size_t)dn * 10);
#pragma unroll
        for (int i = 0; i < 5; i++) {
          float2 ss = sis[i], sd = sid[i], ps = lps[i], pd = lpd[i];
          f16x2 lu = lP[sl][i], lv = lP[sl][5 + i];
          float e0 = ps.x + alpha * (ss.x - (float)lv[0]);
          float e1 = ps.y + alpha * (ss.y - (float)lv[1]);
          float r0 = pd.x + alpha * (sd.x - (float)lu[0]);
          float r1 = pd.y + alpha * (sd.y - (float)lu[1]);
          te[2 * i] = e0; te[2 * i + 1] = e1;
          tr[2 * i] = r0; tr[2 * i + 1] = r1;
          mxe = fmaxf(mxe, fmaxf(e0, e1));
          mxr = fmaxf(mxr, fmaxf(r0, r1));
        }
      }
      float se = 0.f, sr = 0.f;
#pragma unroll
      for (int c = 0; c < NC; c++) {
        float ve = __expf(te[c] - mxe);
        float vr = __expf(tr[c] - mxr);
        te[c] = ve; tr[c] = vr;
        se += ve; sr += vr;
      }
      const float ie = 0.2f / se, ir = 0.2f / sr;
      float me[10], mr[10];
      float nse = 0.f, nsr = 0.f;
#pragma unroll
      for (int i = 0; i < 5; i++) {
        f16x2 u = mP[sl][i], v = mP[sl][5 + i];
        float a0 = fmaxf(0.8f * (float)u[0] + te[2 * i] * ie, 1e-12f);
        float a1 = fmaxf(0.8f * (float)u[1] + te[2 * i + 1] * ie, 1e-12f);
        float b0 = fmaxf(0.8f * (float)v[0] + tr[2 * i] * ir, 1e-12f);
        float b1 = fmaxf(0.8f * (float)v[1] + tr[2 * i + 1] * ir, 1e-12f);
        me[2 * i] = a0; me[2 * i + 1] = a1;
        mr[2 * i] = b0; mr[2 * i + 1] = b1;
        nse += a0 + a1; nsr += b0 + b1;
      }
      const float qe = 1.f / nse, qr = 1.f / nsr;
#pragma unroll
      for (int i = 0; i < 5; i++) {
        me[2 * i] *= qe; me[2 * i + 1] *= qe;
        mr[2 * i] *= qr; mr[2 * i + 1] *= qr;
        f16x2 u, v;
        u[0] = (f16)me[2 * i]; u[1] = (f16)me[2 * i + 1];
        v[0] = (f16)mr[2 * i]; v[1] = (f16)mr[2 * i + 1];
        mP[sl][i] = u; mP[sl][5 + i] = v;
        // K-apply uses the UNROUNDED f32 me/mr (round-9 exact)
      }
      float fe[10] = {0, 0, 0, 0, 0, 0, 0, 0, 0, 0};
      float fr[10] = {0, 0, 0, 0, 0, 0, 0, 0, 0, 0};
#pragma unroll
      for (int c = 0; c < NC; c++) {
        float Ecc = __expf(w * Rs[c * NC + c]);
        fe[c] += me[c] * Ecc;
        fr[c] += mr[c] * Ecc;
#pragma unroll
        for (int dd = c + 1; dd < NC; dd++) {
          float E = __expf(w * Rs[c * NC + dd]);
          fe[dd] += me[c] * E; fe[c] += me[dd] * E;
          fr[dd] += mr[c] * E; fr[c] += mr[dd] * E;
        }
      }
      f16x2* Lpe = (f16x2*)(L + (size_t)p * 10);
      f16x2* Lpr = (f16x2*)(L + (size_t)(p + NP) * 10);
#pragma unroll
      for (int i = 0; i < 5; i++) {
        f16x2 u, v;
        u[0] = (f16)(__logf(fmaxf(fe[2 * i], 1e-12f)) * en);
        u[1] = (f16)(__logf(fmaxf(fe[2 * i + 1], 1e-12f)) * en);
        v[0] = (f16)(__logf(fmaxf(fr[2 * i], 1e-12f)) * en);
        v[1] = (f16)(__logf(fmaxf(fr[2 * i + 1], 1e-12f)) * en);
        lP[sl][i] = u; lP[sl][5 + i] = v;
        Lpe[i] = u; Lpr[i] = v;
      }
    }
  }
}

// ---------------- final beliefs ----------------
__global__ __launch_bounds__(256) void k_beliefs(const float* __restrict__ logphi,
    const float* __restrict__ sum_in, const float* __restrict__ Rbuf, float* __restrict__ out) {
  int n = blockIdx.x * 256 + threadIdx.x;
  if (n >= NN) return;
  float alpha = Rbuf[100];
  float t[NC];
  float mx = -1e30f;
#pragma unroll
  for (int c = 0; c < NC; c++) {
    float v = logphi[n * NC + c] + alpha * sum_in[n * NC + c];
    t[c] = v;
    mx = fmaxf(mx, v);
  }
  float ssum = 0.f;
#pragma unroll
  for (int c = 0; c < NC; c++) { float ev = __expf(t[c] - mx); t[c] = ev; ssum += ev; }
  float inv = 1.f / ssum;
#pragma unroll
  for (int c = 0; c < NC; c++) out[(size_t)n * NC + c] = t[c] * inv;
}

extern "C" void kernel_launch(void* const* d_in, const int* in_sizes, int n_in,
                              void* d_out, int out_size, void* d_ws, size_t ws_size,
                              hipStream_t stream) {
  const float* x    = (const float*)d_in[0];
  const int*   ei   = (const int*)d_in[1];
  const float* ew1  = (const float*)d_in[3];
  const float* eb1  = (const float*)d_in[4];
  const float* ew2  = (const float*)d_in[5];
  const float* eb2  = (const float*)d_in[6];
  const float* mw1  = (const float*)d_in[7];
  const float* mb1  = (const float*)d_in[8];
  const float* mw2  = (const float*)d_in[9];
  const float* mb2  = (const float*)d_in[10];
  const float* Rraw = (const float*)d_in[11];
  const float* rsl  = (const float*)d_in[12];
  const float* ml   = (const float*)d_in[13];
  float* out = (float*)d_out;

  char* ws = (char*)d_ws;
  float* Rbuf   = (float*)(ws + OFF_R);
  f16*   h      = (f16*)(ws + OFF_H);
  int*   offs   = (int*)(ws + OFF_OFFS);
  int*   cursor = (int*)(ws + OFF_CUR);
  int*   csr    = (int*)(ws + OFF_CSR);
  int*   bsum   = (int*)(ws + OFF_BSUM);
  int*   bbase  = (int*)(ws + OFF_BBASE);
  float* logphi = (float*)(ws + OFF_LOGPHI);
  float* deg    = (float*)(ws + OFF_DEG);
  float* logdeg = (float*)(ws + OFF_LOGDEG);
  float* rsq    = (float*)(ws + OFF_RSQ);
  float* wpair  = (float*)(ws + OFF_WPAIR);
  float* enp    = (float*)(ws + OFF_EN);
  f16*   m      = (f16*)(ws + OFF_M);
  f16*   L      = (f16*)(ws + OFF_L);
  float* sumin  = (float*)(ws + OFF_SUMIN);
  f16*   w1t    = (f16*)(ws + OFF_W1T);
  f16*   w1te   = (f16*)(ws + OFF_W1TE);

  k_setup<<<1, 256, 0, stream>>>(Rraw, rsl, ml, mw1, ew1, Rbuf, w1t, w1te);
  hipMemsetAsync(deg, 0, NN * sizeof(float), stream);
  k_deg<<<NEDGE / 256, 256, 0, stream>>>(ei, deg);
  k_nodepost<<<(NN + 255) / 256, 256, 0, stream>>>(deg, logdeg, rsq);
  k_encoder<<<(NN + 63) / 64, 256, 0, stream>>>(x, w1te, eb1, h);
  k_logits<<<NN / 16, 256, 0, stream>>>(h, ew2, eb2, logphi);
  k_edge_mlp<<<512, 256, 0, stream>>>(h, ei, logdeg, rsq, w1t, mw1, mb1, mw2, mb2, wpair, enp);
  // CSR build (h region dead from here on)
  k_scan1<<<SCAN_NB, 256, 0, stream>>>(deg, bsum);
  k_scan2<<<1, 256, 0, stream>>>(bsum, bbase);
  k_scan3<<<SCAN_NB, 256, 0, stream>>>(deg, bbase, offs, cursor);
  k_fill<<<NEDGE / 256, 256, 0, stream>>>(ei, cursor, csr);

  // Deterministic host-side decision: cooperative if it provably fits.
  int maxblk = 0;
  hipError_t qerr = hipOccupancyMaxActiveBlocksPerMultiprocessor(&maxblk, k_coop, 256, 0);
  bool coop = (qerr == hipSuccess) && (maxblk >= 2);
  if (coop) {
    int nblk = (maxblk >= 4 ? 4 : maxblk) * NCU;  // 512..1024 blocks, all co-resident
    void* args[] = {(void*)&ei, (void*)&wpair, (void*)&enp, (void*)&logphi,
                    (void*)&Rbuf, (void*)&L, (void*)&sumin, (void*)&csr, (void*)&offs};
    hipError_t lerr = hipLaunchCooperativeKernel((void*)k_coop, dim3(nblk), dim3(256),
                                                 args, 0, stream);
    if (lerr != hipSuccess) coop = false;
  }
  if (!coop) {
    // round-9 proven fallback loop
    k_m0<<<NEDGE / 256, 256, 0, stream>>>(ei, logphi, m);
    k_bp_f<<<NEDGE / 256, 256, 0, stream>>>(m, wpair, enp, Rbuf, L);
    const int gblocks = (NN + 23) / 24;
    const int fblocks = (NP + 255) / 256;
    for (int it = 0; it < TBP; it++) {
      k_gather<<<gblocks, 256, 0, stream>>>(L, csr, offs, sumin);
      k_bp_fused<<<fblocks, 256, 0, stream>>>(m, L, sumin, logphi, ei, wpair, enp, Rbuf);
    }
    k_gather<<<gblocks, 256, 0, stream>>>(L, csr, offs, sumin);
  }
  k_beliefs<<<(NN + 255) / 256, 256, 0, stream>>>(logphi, sumin, Rbuf, out);
}

// Round 13
// 929.891 us; speedup vs baseline: 1.3676x; 1.0634x over previous
//
#include <hip/hip_runtime.h>
#include <hip/hip_fp16.h>

#define NN 50000
#define NP 400000
#define NEDGE 800000
#define IND 256
#define HD 128
#define NC 10
#define TBP 10
#define SCAN_NB 196  // ceil(NN/256)

typedef _Float16 f16;
typedef _Float16 f16x2 __attribute__((ext_vector_type(2)));
typedef _Float16 f16x4 __attribute__((ext_vector_type(4)));
typedef _Float16 f16x8 __attribute__((ext_vector_type(8)));
typedef unsigned short u16x8 __attribute__((ext_vector_type(8)));
typedef float f32x4 __attribute__((ext_vector_type(4)));

// ---- workspace offsets (bytes) ----
static constexpr size_t OFF_R      = 0;
static constexpr size_t OFF_H      = 512;            // h fp16 [NN][128] (dead after edge_mlp)
static constexpr size_t OFF_OFFS   = 512;            // CSR off int[NN+1]   (aliases h)
static constexpr size_t OFF_CUR    = 512 + 200016;   // CSR cursor int[NN]  (aliases h)
static constexpr size_t OFF_POS    = 512 + 400032;   // pos int[NEDGE]: edge -> CSR slot (aliases h)
static constexpr size_t OFF_BSUM   = 512 + 3600032;  // int[256] block sums (aliases h)
static constexpr size_t OFF_BBASE  = 512 + 3601056;  // int[256] block bases (aliases h)
static constexpr size_t OFF_LOGPHI = 12800512;   // [NN][10] f32
static constexpr size_t OFF_DEG    = 14800512;   // [NN] f32
static constexpr size_t OFF_LOGDEG = 15000512;   // [NN] f32
static constexpr size_t OFF_RSQ    = 15200512;   // [NN] f32
static constexpr size_t OFF_WPAIR  = 15400512;   // [NP] f32
static constexpr size_t OFF_EN     = 17000512;   // [NP] f32
static constexpr size_t OFF_M      = 18600512;   // m edge-major [NEDGE][10] f16 (16MB)
static constexpr size_t OFF_L      = 50600512;   // L in CSR-slot order [NEDGE][10] f16 (16MB)
static constexpr size_t OFF_SUMIN  = 82600512;   // [NN][10] f32
static constexpr size_t OFF_W1T    = 84600512;   // edge W1^T fp16 [64][256]
static constexpr size_t OFF_W1TE   = 84633280;   // enc W1^T fp16 [128][256]

// ---------------- setup: R matrix, alpha, W1 transposes ----------------
__global__ __launch_bounds__(256) void k_setup(const float* __restrict__ Rraw,
    const float* __restrict__ rsl, const float* __restrict__ ml,
    const float* __restrict__ mw1, const float* __restrict__ ew1,
    float* __restrict__ Rbuf, f16* __restrict__ w1t, f16* __restrict__ w1te) {
  int tid = threadIdx.x;
  if (tid < 100) {
    int c = tid / 10, d = tid % 10;
    float scale = log1pf(expf(rsl[0])) + 1e-6f;
    Rbuf[tid] = scale * tanhf(0.5f * (Rraw[c * 10 + d] + Rraw[d * 10 + c]));
  } else if (tid == 100) {
    Rbuf[100] = 1.5f * (1.f / (1.f + expf(-ml[0])));
  }
  for (int idx = tid; idx < 64 * 256; idx += 256) {
    int j = idx >> 8, k = idx & 255;
    w1t[idx] = (f16)mw1[k * 64 + j];
  }
  for (int idx = tid; idx < 128 * 256; idx += 256) {
    int j = idx >> 8, k = idx & 255;
    w1te[idx] = (f16)ew1[k * HD + j];
  }
}

// ---------------- degree / node post ----------------
__global__ __launch_bounds__(256) void k_deg(const int* __restrict__ ei, float* __restrict__ deg) {
  int e = blockIdx.x * 256 + threadIdx.x;
  if (e < NEDGE) atomicAdd(&deg[ei[e]], 1.f);
}

__global__ __launch_bounds__(256) void k_nodepost(const float* __restrict__ deg,
    float* __restrict__ logdeg, float* __restrict__ rsq) {
  int i = blockIdx.x * 256 + threadIdx.x;
  if (i >= NN) return;
  float d = deg[i];
  logdeg[i] = __logf(d + 1.f);
  rsq[i] = rsqrtf(fmaxf(d, 1.f));
}

// ---------------- CSR build: 3-phase hierarchical scan ----------------
__global__ __launch_bounds__(256) void k_scan1(const float* __restrict__ deg,
    int* __restrict__ bsum) {
  int idx = blockIdx.x * 256 + threadIdx.x;
  int v = (idx < NN) ? (int)deg[idx] : 0;
#pragma unroll
  for (int o = 32; o; o >>= 1) v += __shfl_down(v, o);
  __shared__ int wsum[4];
  if ((threadIdx.x & 63) == 0) wsum[threadIdx.x >> 6] = v;
  __syncthreads();
  if (threadIdx.x == 0) bsum[blockIdx.x] = wsum[0] + wsum[1] + wsum[2] + wsum[3];
}

__global__ __launch_bounds__(256) void k_scan2(const int* __restrict__ bsum,
    int* __restrict__ bbase) {
  __shared__ int s[256];
  int t = threadIdx.x;
  int orig = (t < SCAN_NB) ? bsum[t] : 0;
  s[t] = orig;
  __syncthreads();
  for (int d = 1; d < 256; d <<= 1) {
    int v = (t >= d) ? s[t - d] : 0;
    __syncthreads();
    s[t] += v;
    __syncthreads();
  }
  bbase[t] = s[t] - orig;  // exclusive
}

__global__ __launch_bounds__(256) void k_scan3(const float* __restrict__ deg,
    const int* __restrict__ bbase, int* __restrict__ off, int* __restrict__ cursor) {
  __shared__ int s[256];
  int t = threadIdx.x;
  int idx = blockIdx.x * 256 + t;
  int d = (idx < NN) ? (int)deg[idx] : 0;
  s[t] = d;
  __syncthreads();
  for (int k = 1; k < 256; k <<= 1) {
    int v = (t >= k) ? s[t - k] : 0;
    __syncthreads();
    s[t] += v;
    __syncthreads();
  }
  int base = bbase[blockIdx.x];
  int excl = base + s[t] - d;
  if (idx < NN) {
    off[idx] = excl;
    cursor[idx] = excl;
  }
  if (idx == NN - 1) off[NN] = excl + d;
}

// fill: pos[e] = CSR slot (coalesced write; scatter moved to L-writes)
__global__ __launch_bounds__(256) void k_fill(const int* __restrict__ ei,
    int* __restrict__ cursor, int* __restrict__ pos) {
  int e = blockIdx.x * 256 + threadIdx.x;
  if (e >= NEDGE) return;
  int d = ei[NEDGE + e];
  pos[e] = atomicAdd(&cursor[d], 1);
}

// ---------------- encoder: h = relu(x @ W1 + b1) via MFMA f16 ----------------
__global__ __launch_bounds__(256) void k_encoder(const float* __restrict__ x,
    const f16* __restrict__ w1te, const float* __restrict__ b1, f16* __restrict__ h) {
  __shared__ f16 As[64 * 264];
  const int tid = threadIdx.x;
  const int wid = tid >> 6;
  const int lane = tid & 63;
  const int l15 = lane & 15;
  const int lhi = lane >> 4;
  const int nb = blockIdx.x * 64;
#pragma unroll
  for (int i = 0; i < 16; i++) {
    int fidx = tid + 256 * i;
    int row = fidx >> 6;
    int q = fidx & 63;
    f32x4 v = {0.f, 0.f, 0.f, 0.f};
    if (nb + row < NN) v = *(const f32x4*)(x + (size_t)(nb + row) * IND + q * 4);
    f16x4 o;
#pragma unroll
    for (int j = 0; j < 4; j++) o[j] = (f16)v[j];
    *(f16x4*)(&As[row * 264 + q * 4]) = o;
  }
  __syncthreads();
  f16x8 bfr[8][2];
#pragma unroll
  for (int ks = 0; ks < 8; ks++)
#pragma unroll
    for (int t = 0; t < 2; t++)
      bfr[ks][t] = *(const f16x8*)(w1te + (size_t)(wid * 32 + t * 16 + l15) * 256 + ks * 32 + lhi * 8);
  float b1v[2] = {b1[wid * 32 + l15], b1[wid * 32 + 16 + l15]};
  f32x4 acc[4][2] = {};
#pragma unroll
  for (int ks = 0; ks < 8; ks++) {
    f16x8 af[4];
#pragma unroll
    for (int rt = 0; rt < 4; rt++)
      af[rt] = *(const f16x8*)(&As[(rt * 16 + l15) * 264 + ks * 32 + lhi * 8]);
#pragma unroll
    for (int rt = 0; rt < 4; rt++)
#pragma unroll
      for (int t = 0; t < 2; t++)
        acc[rt][t] = __builtin_amdgcn_mfma_f32_16x16x32_f16(af[rt], bfr[ks][t], acc[rt][t], 0, 0, 0);
  }
#pragma unroll
  for (int rt = 0; rt < 4; rt++) {
#pragma unroll
    for (int t = 0; t < 2; t++) {
#pragma unroll
      for (int i = 0; i < 4; i++) {
        int row = nb + rt * 16 + lhi * 4 + i;
        if (row < NN)
          h[(size_t)row * HD + wid * 32 + t * 16 + l15] = (f16)fmaxf(acc[rt][t][i] + b1v[t], 0.f);
      }
    }
  }
}

// ---------------- logits + log_softmax(logits/1.5) ----------------
__global__ __launch_bounds__(256) void k_logits(const f16* __restrict__ h,
    const float* __restrict__ w2, const float* __restrict__ b2, float* __restrict__ logphi) {
  __shared__ float hs[16 * HD];
  __shared__ float lg[16 * NC];
  const int tid = threadIdx.x;
  const int nb = blockIdx.x * 16;
  for (int i = tid; i < 16 * HD / 8; i += 256) {
    f16x8 v = *(const f16x8*)(h + (size_t)nb * HD + i * 8);
#pragma unroll
    for (int u = 0; u < 8; u++) hs[i * 8 + u] = (float)v[u];
  }
  __syncthreads();
  if (tid < 160) {
    int n = tid / 10, c = tid % 10;
    float a = b2[c];
    for (int k = 0; k < HD; k++) a += hs[n * HD + k] * w2[k * NC + c];
    lg[n * NC + c] = a * (1.f / 1.5f);
  }
  __syncthreads();
  if (tid < 16) {
    float mx = -1e30f;
#pragma unroll
    for (int c = 0; c < NC; c++) mx = fmaxf(mx, lg[tid * NC + c]);
    float s = 0.f;
#pragma unroll
    for (int c = 0; c < NC; c++) s += __expf(lg[tid * NC + c] - mx);
    float lse = __logf(s) + mx;
#pragma unroll
    for (int c = 0; c < NC; c++)
      logphi[(size_t)(nb + tid) * NC + c] = lg[tid * NC + c] - lse;
  }
}

// ---------------- edge MLP (per undirected pair), MFMA f16 ----------------
__global__ __launch_bounds__(256) void k_edge_mlp(const f16* __restrict__ h,
    const int* __restrict__ ei, const float* __restrict__ logdeg, const float* __restrict__ rsq,
    const f16* __restrict__ w1t, const float* __restrict__ mw1, const float* __restrict__ mb1,
    const float* __restrict__ mw2, const float* __restrict__ mb2,
    float* __restrict__ w_pair, float* __restrict__ en_pair) {
  __shared__ f16 At[4][16 * 264];
  __shared__ float hidl[4][16 * 64];
  __shared__ float sfeat[4][2][16];
  const int tid = threadIdx.x;
  const int wid = tid >> 6;
  const int lane = tid & 63;
  const int l15 = lane & 15;
  const int lhi = lane >> 4;

  f16x8 bfr[8][4];
#pragma unroll
  for (int ks = 0; ks < 8; ks++)
#pragma unroll
    for (int t = 0; t < 4; t++)
      bfr[ks][t] = *(const f16x8*)(w1t + (size_t)(l15 + 16 * t) * 256 + ks * 32 + lhi * 8);

  float b1v[4], w256v[4], w257v[4];
#pragma unroll
  for (int t = 0; t < 4; t++) {
    b1v[t] = mb1[l15 + 16 * t];
    w256v[t] = mw1[256 * 64 + l15 + 16 * t];
    w257v[t] = mw1[257 * 64 + l15 + 16 * t];
  }
  float w2r[16];
#pragma unroll
  for (int jj = 0; jj < 16; jj++) w2r[jj] = mw2[lhi * 16 + jj];
  const float b2s = mb2[0];

  const int ntiles = NP / 64;
  for (int tile = blockIdx.x; tile < ntiles; tile += gridDim.x) {
    const int pbase = tile * 64 + wid * 16;
#pragma unroll
    for (int rr = 0; rr < 4; rr++) {
      int r = rr * 4 + lhi;
      int p = pbase + r;
      int s = ei[p], d = ei[NEDGE + p];
      f16x8 hv = *(const f16x8*)(h + (size_t)s * HD + l15 * 8);
      f16x8 gv = *(const f16x8*)(h + (size_t)d * HD + l15 * 8);
      f16x8 pv = hv * gv;
      f16x8 qv = hv - gv;
      u16x8 qb = *(u16x8*)&qv;
#pragma unroll
      for (int u = 0; u < 8; u++) qb[u] &= 0x7FFF;
      qv = *(f16x8*)&qb;
      *(f16x8*)(&At[wid][r * 264 + l15 * 8]) = pv;
      *(f16x8*)(&At[wid][r * 264 + 128 + l15 * 8]) = qv;
    }
    if (lane < 16) {
      int p = pbase + lane;
      int s = ei[p], d = ei[NEDGE + p];
      float a = logdeg[s], b = logdeg[d];
      sfeat[wid][0][lane] = a + b;
      sfeat[wid][1][lane] = fabsf(a - b);
      en_pair[p] = rsq[s] * rsq[d];
    }
    __syncthreads();
    f32x4 acc[4] = {{0.f, 0.f, 0.f, 0.f}, {0.f, 0.f, 0.f, 0.f},
                    {0.f, 0.f, 0.f, 0.f}, {0.f, 0.f, 0.f, 0.f}};
#pragma unroll
    for (int ks = 0; ks < 8; ks++) {
      f16x8 af = *(const f16x8*)(&At[wid][l15 * 264 + ks * 32 + lhi * 8]);
#pragma unroll
      for (int t = 0; t < 4; t++)
        acc[t] = __builtin_amdgcn_mfma_f32_16x16x32_f16(af, bfr[ks][t], acc[t], 0, 0, 0);
    }
#pragma unroll
    for (int t = 0; t < 4; t++) {
#pragma unroll
      for (int i = 0; i < 4; i++) {
        int r = lhi * 4 + i;
        float v = acc[t][i] + sfeat[wid][0][r] * w256v[t] + sfeat[wid][1][r] * w257v[t] + b1v[t];
        hidl[wid][r * 64 + l15 + 16 * t] = fmaxf(v, 0.f);
      }
    }
    __syncthreads();
    {
      float sacc = 0.f;
#pragma unroll
      for (int jj = 0; jj < 16; jj++) sacc += hidl[wid][l15 * 64 + lhi * 16 + jj] * w2r[jj];
      sacc += __shfl_xor(sacc, 16);
      sacc += __shfl_xor(sacc, 32);
      if (lane < 16) {
        float wr = sacc + b2s;
        w_pair[pbase + lane] = 0.8f / (1.f + __expf(-wr));
      }
    }
    __syncthreads();
  }
}

// ---------------- m0 = exp(log_phi[src]) (edge-major, f16) ----------------
__global__ __launch_bounds__(256) void k_m0(const int* __restrict__ ei,
    const float* __restrict__ logphi, f16* __restrict__ m) {
  int e = blockIdx.x * 256 + threadIdx.x;
  if (e >= NEDGE) return;
  int s = ei[e];
  f16x2* mp = (f16x2*)(m + (size_t)e * 10);
  const float2* lp = (const float2*)(logphi + (size_t)s * 10);
#pragma unroll
  for (int i = 0; i < 5; i++) {
    float2 v = lp[i];
    f16x2 o;
    o[0] = (f16)__expf(v.x);
    o[1] = (f16)__expf(v.y);
    mp[i] = o;
  }
}

// ---------------- initial L (CSR-slot order) from m0; scattered write ----------------
__global__ __launch_bounds__(256) void k_bp_f(const f16* __restrict__ m,
    const float* __restrict__ wp, const float* __restrict__ enp,
    const int* __restrict__ pos, const float* __restrict__ Rbuf, f16* __restrict__ L) {
  __shared__ float Rs[100];
  if (threadIdx.x < 100) Rs[threadIdx.x] = Rbuf[threadIdx.x];
  __syncthreads();
  int e = blockIdx.x * 256 + threadIdx.x;
  if (e >= NEDGE) return;
  int p = (e < NP) ? e : e - NP;
  float w = wp[p], en = enp[p];
  float mr[10];
  {
    const f16x2* mp = (const f16x2*)(m + (size_t)e * 10);
#pragma unroll
    for (int i = 0; i < 5; i++) { f16x2 v = mp[i]; mr[2 * i] = (float)v[0]; mr[2 * i + 1] = (float)v[1]; }
  }
  float f[10] = {0, 0, 0, 0, 0, 0, 0, 0, 0, 0};
#pragma unroll
  for (int c = 0; c < NC; c++) {
    float Ecc = __expf(w * Rs[c * NC + c]);
    f[c] += mr[c] * Ecc;
#pragma unroll
    for (int d = c + 1; d < NC; d++) {
      float Ecd = __expf(w * Rs[c * NC + d]);
      f[d] += mr[c] * Ecd;
      f[c] += mr[d] * Ecd;
    }
  }
  f16x2* Lp = (f16x2*)(L + (size_t)pos[e] * 10);
#pragma unroll
  for (int i = 0; i < 5; i++) {
    f16x2 o;
    o[0] = (f16)(__logf(fmaxf(f[2 * i], 1e-12f)) * en);
    o[1] = (f16)(__logf(fmaxf(f[2 * i + 1], 1e-12f)) * en);
    Lp[i] = o;
  }
}

// ---------------- gather2: STREAMING sum of contiguous CSR-ordered L rows ----------------
__global__ __launch_bounds__(256) void k_gather(const f16* __restrict__ L,
    const int* __restrict__ off, float* __restrict__ sumin) {
  int wave = (blockIdx.x * 256 + threadIdx.x) >> 6;
  int lane = threadIdx.x & 63;
  int nl = lane / 10;   // 6 nodes per wave, lanes 60..63 idle
  int c = lane % 10;
  int n = wave * 6 + nl;
  if (nl >= 6 || n >= NN) return;
  int o0 = off[n], o1 = off[n + 1];
  float acc = 0.f;
  for (int k = o0; k < o1; k++) acc += (float)L[(size_t)k * 10 + c];
  sumin[(size_t)n * 10 + c] = acc;
}

// ---------------- fused BP step: recompute L_old from m, write new L scattered ----------------
__global__ __launch_bounds__(256) void k_bp_fused(f16* __restrict__ m,
    f16* __restrict__ L, const float* __restrict__ sumin,
    const float* __restrict__ logphi, const int* __restrict__ ei,
    const int* __restrict__ pos,
    const float* __restrict__ wp, const float* __restrict__ enp,
    const float* __restrict__ Rbuf) {
  __shared__ float Rs[104];
  if (threadIdx.x < 101) Rs[threadIdx.x] = Rbuf[threadIdx.x];
  __syncthreads();
  int p = blockIdx.x * 256 + threadIdx.x;
  if (p >= NP) return;
  const float alpha = Rs[100];
  const int s = ei[p], d = ei[NEDGE + p];
  const float w = wp[p], en = enp[p];
  const int pe = pos[p], pr = pos[p + NP];

  // m_old (f16-rounded, as stored)
  float meo[10], mro[10];
  {
    const f16x2* mpe = (const f16x2*)(m + (size_t)p * 10);
    const f16x2* mpr = (const f16x2*)(m + (size_t)(p + NP) * 10);
#pragma unroll
    for (int i = 0; i < 5; i++) {
      f16x2 u = mpe[i], v = mpr[i];
      meo[2 * i] = (float)u[0]; meo[2 * i + 1] = (float)u[1];
      mro[2 * i] = (float)v[0]; mro[2 * i + 1] = (float)v[1];
    }
  }
  // recompute L_old = log(K m_old)*en (f32)
  float feo[10] = {0, 0, 0, 0, 0, 0, 0, 0, 0, 0};
  float fro[10] = {0, 0, 0, 0, 0, 0, 0, 0, 0, 0};
#pragma unroll
  for (int c = 0; c < NC; c++) {
    float Ecc = __expf(w * Rs[c * NC + c]);
    feo[c] += meo[c] * Ecc;
    fro[c] += mro[c] * Ecc;
#pragma unroll
    for (int dd = c + 1; dd < NC; dd++) {
      float E = __expf(w * Rs[c * NC + dd]);
      feo[dd] += meo[c] * E; feo[c] += meo[dd] * E;
      fro[dd] += mro[c] * E; fro[c] += mro[dd] * E;
    }
  }
  float Leo[10], Lro[10];
#pragma unroll
  for (int c = 0; c < NC; c++) {
    Leo[c] = __logf(fmaxf(feo[c], 1e-12f)) * en;
    Lro[c] = __logf(fmaxf(fro[c], 1e-12f)) * en;
  }
  // te (edge p, src=s) excludes reverse edge's L (Lro); tr excludes Leo
  float te[10], tr[10];
  float mxe = -1e30f, mxr = -1e30f;
  {
    const float2* sis = (const float2*)(sumin + (size_t)s * 10);
    const float2* sid = (const float2*)(sumin + (size_t)d * 10);
    const float2* lps = (const float2*)(logphi + (size_t)s * 10);
    const float2* lpd = (const float2*)(logphi + (size_t)d * 10);
#pragma unroll
    for (int i = 0; i < 5; i++) {
      float2 ss = sis[i], sd = sid[i], ps = lps[i], pd = lpd[i];
      float e0 = ps.x + alpha * (ss.x - Lro[2 * i]);
      float e1 = ps.y + alpha * (ss.y - Lro[2 * i + 1]);
      float r0 = pd.x + alpha * (sd.x - Leo[2 * i]);
      float r1 = pd.y + alpha * (sd.y - Leo[2 * i + 1]);
      te[2 * i] = e0; te[2 * i + 1] = e1;
      tr[2 * i] = r0; tr[2 * i + 1] = r1;
      mxe = fmaxf(mxe, fmaxf(e0, e1));
      mxr = fmaxf(mxr, fmaxf(r0, r1));
    }
  }
  float se = 0.f, sr = 0.f;
#pragma unroll
  for (int c = 0; c < NC; c++) {
    float ve = __expf(te[c] - mxe);
    float vr = __expf(tr[c] - mxr);
    te[c] = ve; tr[c] = vr;
    se += ve; sr += vr;
  }
  const float ie = 0.2f / se, ir = 0.2f / sr;
  // mix with m_old, renorm; K-apply uses UNROUNDED f32 m_new (round-9 exact)
  float me[10], mr[10];
  float nse = 0.f, nsr = 0.f;
#pragma unroll
  for (int c = 0; c < NC; c++) {
    float a0 = fmaxf(0.8f * meo[c] + te[c] * ie, 1e-12f);
    float b0 = fmaxf(0.8f * mro[c] + tr[c] * ir, 1e-12f);
    me[c] = a0; mr[c] = b0;
    nse += a0; nsr += b0;
  }
  const float qe = 1.f / nse, qr = 1.f / nsr;
  {
    f16x2* mpe = (f16x2*)(m + (size_t)p * 10);
    f16x2* mpr = (f16x2*)(m + (size_t)(p + NP) * 10);
#pragma unroll
    for (int i = 0; i < 5; i++) {
      me[2 * i] *= qe; me[2 * i + 1] *= qe;
      mr[2 * i] *= qr; mr[2 * i + 1] *= qr;
      f16x2 u, v;
      u[0] = (f16)me[2 * i]; u[1] = (f16)me[2 * i + 1];
      v[0] = (f16)mr[2 * i]; v[1] = (f16)mr[2 * i + 1];
      mpe[i] = u; mpr[i] = v;
    }
  }
  // new L from unrounded m_new; scattered write to CSR slots
  float fen[10] = {0, 0, 0, 0, 0, 0, 0, 0, 0, 0};
  float frn[10] = {0, 0, 0, 0, 0, 0, 0, 0, 0, 0};
#pragma unroll
  for (int c = 0; c < NC; c++) {
    float Ecc = __expf(w * Rs[c * NC + c]);
    fen[c] += me[c] * Ecc;
    frn[c] += mr[c] * Ecc;
#pragma unroll
    for (int dd = c + 1; dd < NC; dd++) {
      float E = __expf(w * Rs[c * NC + dd]);
      fen[dd] += me[c] * E; fen[c] += me[dd] * E;
      frn[dd] += mr[c] * E; frn[c] += mr[dd] * E;
    }
  }
  {
    f16x2* Lpe = (f16x2*)(L + (size_t)pe * 10);
    f16x2* Lpr = (f16x2*)(L + (size_t)pr * 10);
#pragma unroll
    for (int i = 0; i < 5; i++) {
      f16x2 u, v;
      u[0] = (f16)(__logf(fmaxf(fen[2 * i], 1e-12f)) * en);
      u[1] = (f16)(__logf(fmaxf(fen[2 * i + 1], 1e-12f)) * en);
      v[0] = (f16)(__logf(fmaxf(frn[2 * i], 1e-12f)) * en);
      v[1] = (f16)(__logf(fmaxf(frn[2 * i + 1], 1e-12f)) * en);
      Lpe[i] = u; Lpr[i] = v;
    }
  }
}

// ---------------- final beliefs ----------------
__global__ __launch_bounds__(256) void k_beliefs(const float* __restrict__ logphi,
    const float* __restrict__ sum_in, const float* __restrict__ Rbuf, float* __restrict__ out) {
  int n = blockIdx.x * 256 + threadIdx.x;
  if (n >= NN) return;
  float alpha = Rbuf[100];
  float t[NC];
  float mx = -1e30f;
#pragma unroll
  for (int c = 0; c < NC; c++) {
    float v = logphi[n * NC + c] + alpha * sum_in[n * NC + c];
    t[c] = v;
    mx = fmaxf(mx, v);
  }
  float ssum = 0.f;
#pragma unroll
  for (int c = 0; c < NC; c++) { float ev = __expf(t[c] - mx); t[c] = ev; ssum += ev; }
  float inv = 1.f / ssum;
#pragma unroll
  for (int c = 0; c < NC; c++) out[(size_t)n * NC + c] = t[c] * inv;
}

extern "C" void kernel_launch(void* const* d_in, const int* in_sizes, int n_in,
                              void* d_out, int out_size, void* d_ws, size_t ws_size,
                              hipStream_t stream) {
  const float* x    = (const float*)d_in[0];
  const int*   ei   = (const int*)d_in[1];
  const float* ew1  = (const float*)d_in[3];
  const float* eb1  = (const float*)d_in[4];
  const float* ew2  = (const float*)d_in[5];
  const float* eb2  = (const float*)d_in[6];
  const float* mw1  = (const float*)d_in[7];
  const float* mb1  = (const float*)d_in[8];
  const float* mw2  = (const float*)d_in[9];
  const float* mb2  = (const float*)d_in[10];
  const float* Rraw = (const float*)d_in[11];
  const float* rsl  = (const float*)d_in[12];
  const float* ml   = (const float*)d_in[13];
  float* out = (float*)d_out;

  char* ws = (char*)d_ws;
  float* Rbuf   = (float*)(ws + OFF_R);
  f16*   h      = (f16*)(ws + OFF_H);
  int*   offs   = (int*)(ws + OFF_OFFS);
  int*   cursor = (int*)(ws + OFF_CUR);
  int*   pos    = (int*)(ws + OFF_POS);
  int*   bsum   = (int*)(ws + OFF_BSUM);
  int*   bbase  = (int*)(ws + OFF_BBASE);
  float* logphi = (float*)(ws + OFF_LOGPHI);
  float* deg    = (float*)(ws + OFF_DEG);
  float* logdeg = (float*)(ws + OFF_LOGDEG);
  float* rsq    = (float*)(ws + OFF_RSQ);
  float* wpair  = (float*)(ws + OFF_WPAIR);
  float* enp    = (float*)(ws + OFF_EN);
  f16*   m      = (f16*)(ws + OFF_M);
  f16*   L      = (f16*)(ws + OFF_L);
  float* sumin  = (float*)(ws + OFF_SUMIN);
  f16*   w1t    = (f16*)(ws + OFF_W1T);
  f16*   w1te   = (f16*)(ws + OFF_W1TE);

  k_setup<<<1, 256, 0, stream>>>(Rraw, rsl, ml, mw1, ew1, Rbuf, w1t, w1te);
  hipMemsetAsync(deg, 0, NN * sizeof(float), stream);
  k_deg<<<NEDGE / 256, 256, 0, stream>>>(ei, deg);
  k_nodepost<<<(NN + 255) / 256, 256, 0, stream>>>(deg, logdeg, rsq);
  k_encoder<<<(NN + 63) / 64, 256, 0, stream>>>(x, w1te, eb1, h);
  k_logits<<<NN / 16, 256, 0, stream>>>(h, ew2, eb2, logphi);
  k_edge_mlp<<<512, 256, 0, stream>>>(h, ei, logdeg, rsq, w1t, mw1, mb1, mw2, mb2, wpair, enp);
  // CSR build (h region dead from here on)
  k_scan1<<<SCAN_NB, 256, 0, stream>>>(deg, bsum);
  k_scan2<<<1, 256, 0, stream>>>(bsum, bbase);
  k_scan3<<<SCAN_NB, 256, 0, stream>>>(deg, bbase, offs, cursor);
  k_fill<<<NEDGE / 256, 256, 0, stream>>>(ei, cursor, pos);
  k_m0<<<NEDGE / 256, 256, 0, stream>>>(ei, logphi, m);
  k_bp_f<<<NEDGE / 256, 256, 0, stream>>>(m, wpair, enp, pos, Rbuf, L);

  const int gblocks = (NN + 23) / 24;
  const int fblocks = (NP + 255) / 256;
  for (int it = 0; it < TBP; it++) {
    k_gather<<<gblocks, 256, 0, stream>>>(L, offs, sumin);
    k_bp_fused<<<fblocks, 256, 0, stream>>>(m, L, sumin, logphi, ei, pos, wpair, enp, Rbuf);
  }
  k_gather<<<gblocks, 256, 0, stream>>>(L, offs, sumin);
  k_beliefs<<<(NN + 255) / 256, 256, 0, stream>>>(logphi, sumin, Rbuf, out);
}